// Round 15
// baseline (132.451 us; speedup 1.0000x reference)
//
#include <hip/hip_runtime.h>

#define NB 4
#define CCH 256
#define NN 4096
#define DD 32

typedef __attribute__((ext_vector_type(8))) short bf16x8;
typedef __attribute__((ext_vector_type(8))) _Float16 f16x8;
typedef __attribute__((ext_vector_type(4))) _Float16 f16x4;
typedef __attribute__((ext_vector_type(2))) __fp16 fp16x2;
typedef __attribute__((ext_vector_type(4))) float f32x4;

#define MFB(a,b,c) __builtin_amdgcn_mfma_f32_16x16x32_bf16(a,b,c,0,0,0)
#define MFH(a,b,c) __builtin_amdgcn_mfma_f32_16x16x32_f16(a,b,c,0,0,0)
#define L2E 1.44269504f

__device__ inline unsigned short f2bf(float f){
    union { float f; unsigned u; } v; v.f = f;
    unsigned r = v.u + 0x7fffu + ((v.u >> 16) & 1u);
    return (unsigned short)(r >> 16);
}
__device__ inline float bfval(unsigned short h){
    union { unsigned u; float f; } v; v.u = ((unsigned)h) << 16; return v.f;
}
// native transcendental: D = 2^S0 (exactly what SL-folded softmax needs)
__device__ inline float vexp2(float x){
    float r; asm("v_exp_f32 %0, %1" : "=v"(r) : "v"(x)); return r;
}
__device__ inline f16x4 pk4(float p0, float p1, float p2, float p3){
    union { fp16x2 h2[2]; f16x4 v; } u;
    u.h2[0] = __builtin_amdgcn_cvt_pkrtz(p0, p1);
    u.h2[1] = __builtin_amdgcn_cvt_pkrtz(p2, p3);
    return u.v;
}

// ---------------------------------------------------------------- proj_fused
// R28: proj_qk and proj_v fused into ONE dispatch (grid.x selects path).
// Evidence: secondary-kernel real work ~20-25us (roofline) vs ~60us wall
// invariant since R17 -> launch/serialization gaps dominate; cut launches.
// prep_w REVERTED (R27(b) measured -4.6us regression): in-block w convert.
// ob<2: V path (V output BLOCKED v16[b][ib=n/8][c][8], 16B per (ib,c)).
// ob==2: q/k path, 8 waves: fp=w>>2 (0=q,1=k), ng=w&3 (n-group), 2 f each.
// q = single f16; k = f16 hi/lo pair (QK = 2 MFMA in attn/stats).
__global__ __launch_bounds__(512) void proj_fused(
    const float* __restrict__ x,
    const float* __restrict__ wq, const float* __restrict__ bq,
    const float* __restrict__ wk, const float* __restrict__ bk,
    const float* __restrict__ wv, const float* __restrict__ bv,
    _Float16* __restrict__ q16,
    _Float16* __restrict__ k_hi, _Float16* __restrict__ k_lo,
    _Float16* __restrict__ v16)
{
    const int ob = blockIdx.x;   // 0,1: V c-halves; 2: q/k
    const int nb = blockIdx.y;
    const int b  = blockIdx.z;
    const int t = threadIdx.x;
    const int l = t & 63;
    const int lr = l & 15, lg = l >> 4;
    const float* xb = x + (size_t)b*CCH*NN;

    if (ob < 2) {
        // ---------------- V path ----------------
        const int w = t >> 6;
        const int cg = w >> 2;
        const int ng = w & 3;
        const int n0 = nb*64 + ng*16;
        const int n  = n0 + lr;
        const int cbase0 = ob*128 + cg*64;

        f32x4 acc[4] = {};

        for (int kc = 0; kc < 8; kc++) {
            const int kbase = kc*32 + lg*8;
            float xv[8];
            #pragma unroll
            for (int e = 0; e < 8; e++)
                xv[e] = xb[(size_t)(kbase + e)*NN + n];
            bf16x8 xh, xl;
            #pragma unroll
            for (int e = 0; e < 8; e++) {
                unsigned short h = f2bf(xv[e]);
                xh[e] = (short)h;
                xl[e] = (short)f2bf(xv[e] - bfval(h));
            }
            #pragma unroll
            for (int f = 0; f < 4; f++) {
                const float* wrow = wv + (size_t)(cbase0 + f*16 + lr)*CCH;
                float4 a4 = *(const float4*)(wrow + kbase);
                float4 b4 = *(const float4*)(wrow + kbase + 4);
                float wv8[8] = {a4.x,a4.y,a4.z,a4.w,b4.x,b4.y,b4.z,b4.w};
                bf16x8 wh, wl;
                #pragma unroll
                for (int e = 0; e < 8; e++) {
                    unsigned short h = f2bf(wv8[e]);
                    wh[e] = (short)h;
                    wl[e] = (short)f2bf(wv8[e] - bfval(h));
                }
                acc[f] = MFB(wl, xh, acc[f]);
                acc[f] = MFB(wh, xl, acc[f]);
                acc[f] = MFB(wh, xh, acc[f]);
            }
        }

        const size_t bslice = (size_t)b*(NN/8);
        #pragma unroll
        for (int f = 0; f < 4; f++) {
            #pragma unroll
            for (int r = 0; r < 4; r++) {
                int c = cbase0 + f*16 + lg*4 + r;
                float val = acc[f][r] + bv[c];
                v16[(((bslice + (n >> 3))*CCH + c) << 3) + (n & 7)] =
                    (_Float16)val;
            }
        }
    } else {
        // ---------------- q/k path (8 waves: fp = w>>2, ng = w&3) ----------
        const int w = t >> 6;
        const int fp = w >> 2;       // 0: q, 1: k
        const int ng = w & 3;
        const int n0 = nb*64 + ng*16;
        const int n  = n0 + lr;

        f32x4 acc[2] = {};

        for (int kc = 0; kc < 8; kc++) {
            const int cbase = kc*32 + lg*8;
            float xv[8];
            #pragma unroll
            for (int e = 0; e < 8; e++)
                xv[e] = xb[(size_t)(cbase + e)*NN + n];
            bf16x8 xh, xl;
            #pragma unroll
            for (int e = 0; e < 8; e++) {
                unsigned short h = f2bf(xv[e]);
                xh[e] = (short)h;
                xl[e] = (short)f2bf(xv[e] - bfval(h));
            }
            #pragma unroll
            for (int fl = 0; fl < 2; fl++) {
                const float* wrow = (fp == 0 ? wq : wk)
                                  + (size_t)(fl*16 + lr)*CCH;
                float4 a4 = *(const float4*)(wrow + cbase);
                float4 b4 = *(const float4*)(wrow + cbase + 4);
                float wv8[8] = {a4.x,a4.y,a4.z,a4.w,b4.x,b4.y,b4.z,b4.w};
                bf16x8 wh, wl;
                #pragma unroll
                for (int e = 0; e < 8; e++) {
                    unsigned short h = f2bf(wv8[e]);
                    wh[e] = (short)h;
                    wl[e] = (short)f2bf(wv8[e] - bfval(h));
                }
                acc[fl] = MFB(xh, wl, acc[fl]);
                acc[fl] = MFB(xl, wh, acc[fl]);
                acc[fl] = MFB(xh, wh, acc[fl]);
            }
        }

        #pragma unroll
        for (int fl = 0; fl < 2; fl++) {
            const int d = fl*16 + lr;
            float bias = fp ? bk[d] : bq[d];
            #pragma unroll
            for (int r = 0; r < 4; r++) {
                int nn = n0 + lg*4 + r;
                float val = acc[fl][r] + bias;
                size_t a = ((size_t)(b*NN + nn))*DD + d;
                if (fp == 0) {
                    q16[a] = (_Float16)val;
                } else {
                    _Float16 h = (_Float16)val;
                    k_hi[a] = h;
                    k_lo[a] = (_Float16)(val - (float)h);
                }
            }
        }
    }
}

// ---------------------------------------------------------------- stats
// R28: combine fused in. jc is now an internal loop (jt 0..31 covers all
// 4096 j: j = w*16+lr + 128*jt); block writes Sx = log2(Z) directly.
// Removes the combine launch + Zp buffer round-trip.
__global__ __launch_bounds__(512) void stats_kernel(
    const _Float16* __restrict__ q16,
    const _Float16* __restrict__ kh, const _Float16* __restrict__ kl,
    float* __restrict__ Sx)
{
    __shared__ float zW[8][64];
    const int t = threadIdx.x;
    const int w = t >> 6;
    const int l = t & 63;
    const int lr = l & 15, lg = l >> 4;
    const int it = blockIdx.x;   // 0..63 : i-tile
    const int b  = blockIdx.y;
    const int ibase = it*64;
    const f32x4 zero = {0.f,0.f,0.f,0.f};

    f16x8 qf[4];
    #pragma unroll
    for (int f = 0; f < 4; f++) {
        size_t a = ((size_t)(b*NN + ibase + f*16 + lr))*DD + lg*8;
        qf[f] = *(const f16x8*)(q16 + a);
    }
    float Z[4] = {0.f, 0.f, 0.f, 0.f};

    const size_t k0 = ((size_t)(b*NN + w*16 + lr))*DD + lg*8;
    const _Float16* kp  = kh + k0;
    const _Float16* klp = kl + k0;

    for (int jt = 0; jt < 32; ++jt) {
        f16x8 kh2 = *(const f16x8*)kp;
        f16x8 kl2 = *(const f16x8*)klp;
        #pragma unroll
        for (int f = 0; f < 4; f++) {
            f32x4 e = MFH(kl2, qf[f], zero);
            e = MFH(kh2, qf[f], e);
            Z[f] += vexp2(e[0]*L2E) + vexp2(e[1]*L2E)
                  + vexp2(e[2]*L2E) + vexp2(e[3]*L2E);
        }
        kp  += 128*DD;
        klp += 128*DD;
    }
    #pragma unroll
    for (int f = 0; f < 4; f++) {
        Z[f] += __shfl_xor(Z[f], 16, 64);
        Z[f] += __shfl_xor(Z[f], 32, 64);
        if (lg == 0) zW[w][f*16 + lr] = Z[f];
    }
    __syncthreads();
    if (t < 64) {
        float z = 0.f;
        #pragma unroll
        for (int w2 = 0; w2 < 8; ++w2) z += zW[w2][t];
        Sx[(size_t)b*NN + ibase + t] = log2f(z);
    }
}

// ---------------------------------------------------------------- attn
// R27(a), unchanged (attn 57.5us, MFMA busy 21.8us ~ full-rate floor):
// sigma-permuted q rows -> K=32 full-rate PV with zero shuffles;
// phase-split step (all 4 jf QK+exp first, then ONE un-fenced PV cluster).
__global__ __launch_bounds__(256, 2) void attn_kernel(
    const _Float16* __restrict__ q16,
    const _Float16* __restrict__ kh16, const _Float16* __restrict__ kl16,
    const _Float16* __restrict__ v16,
    const float* __restrict__ Sx,
    const float* __restrict__ x, const float* __restrict__ gamma,
    float* __restrict__ out)
{
    __shared__ __align__(16) f32x4 Rb[4096];   // 64KB end-reduce buffer

    const int t = threadIdx.x;
    const int wv = t >> 6;       // i-quarter 0..3
    const int l = t & 63;
    const int lr = l & 15, lg = l >> 4;

    // XCD slice: lin&7 = (b,ct) -> one slice per XCD (~1.8MB, L2-resident).
    const int lin = blockIdx.x;
    const int slice = lin & 7;
    const int b   = slice >> 1;
    const int ct  = slice & 1;
    const int jt  = lin >> 3;    // 0..63
    const int jbase = jt*64, cbase = ct*128;

    // K B-fragments: 4 j-frags, f16 hi/lo (persistent; 32 VGPR)
    f16x8 kfh[4], kfl[4];
    #pragma unroll
    for (int jf = 0; jf < 4; jf++) {
        size_t a = ((size_t)(b*NN + jbase + jf*16 + lr))*DD + lg*8;
        kfh[jf] = *(const f16x8*)(kh16 + a);
        kfl[jf] = *(const f16x8*)(kl16 + a);
    }

    const float* Sb = Sx + (size_t)b*NN;
    const _Float16* vb = v16 + (size_t)b*(NN/8)*CCH*8;

    const int i0 = wv*1024;     // this wave's i-quarter; 32 steps of 32

    // sigma-permuted q pointers: step A rows 8(lr>>2)+(lr&3), step B +4
    const int sigma = 8*(lr >> 2) + (lr & 3);
    const _Float16* qpA = q16 + ((size_t)(b*NN + i0 + sigma))*DD + lg*8;
    const _Float16* qpB = qpA + 4*DD;
    // s pointers follow sigma: lane lg covers i = 8lg+r (A), 8lg+4+r (B)
    const float* spA = Sb + i0 + 8*lg;
    const float* spB = spA + 4;
    // V B-frag: lane (lr,lg) reads 16B block ib = i0/8 + lg, c = ..+lr
    const _Float16* vp = vb + (((size_t)(i0/8 + lg)*CCH + cbase + lr) << 3);

    f32x4 acc[4][8] = {};   // [jf][cf] -- ONLY static subscripts below!

    #pragma clang loop unroll(disable)
    for (int s = 0; s < 32; ++s) {
        // loads for THIS step (L2-resident; TLP hides the latency)
        f16x8 qA = *(const f16x8*)qpA;  qpA += 32*DD;
        f16x8 qB = *(const f16x8*)qpB;  qpB += 32*DD;
        float4 sA4 = *(const float4*)spA; spA += 32;
        float4 sB4 = *(const float4*)spB; spB += 32;
        f16x8 vv[8];
        #pragma unroll
        for (int cf = 0; cf < 8; cf++)
            vv[cf] = *(const f16x8*)(vp + cf*128);
        vp += 32*CCH;

        // ---- Phase 1: all 4 jf QK + exp + pack (independent chains) ----
        f16x8 pa[4];
        #pragma unroll
        for (int jf = 0; jf < 4; jf++) {
            f32x4 eA = {};
            eA = MFH(qA, kfl[jf], eA);
            eA = MFH(qA, kfh[jf], eA);
            f32x4 eB = {};
            eB = MFH(qB, kfl[jf], eB);
            eB = MFH(qB, kfh[jf], eB);
            union { f16x4 h4[2]; f16x8 h8; } pu;
            pu.h4[0] = pk4(vexp2(fmaf(eA[0], L2E, -sA4.x)),
                           vexp2(fmaf(eA[1], L2E, -sA4.y)),
                           vexp2(fmaf(eA[2], L2E, -sA4.z)),
                           vexp2(fmaf(eA[3], L2E, -sA4.w)));
            pu.h4[1] = pk4(vexp2(fmaf(eB[0], L2E, -sB4.x)),
                           vexp2(fmaf(eB[1], L2E, -sB4.y)),
                           vexp2(fmaf(eB[2], L2E, -sB4.z)),
                           vexp2(fmaf(eB[3], L2E, -sB4.w)));
            pa[jf] = pu.h8;
        }

        // ---- Phase 2: ONE un-fenced PV cluster (32 full-rate MFH) ----
        __builtin_amdgcn_s_setprio(1);
        #pragma unroll
        for (int jf = 0; jf < 4; jf++)
            #pragma unroll
            for (int cf = 0; cf < 8; cf++)
                acc[jf][cf] = MFH(pa[jf], vv[cf], acc[jf][cf]);
        __builtin_amdgcn_s_setprio(0);
    }

    // ------------- 3-barrier tree reduce over the 4 i-quarters -------------
    // All acc subscripts literal. slot(jf,cf) = (jf*8+cf)<<6 | lane.
    if (wv == 2) {
        #pragma unroll
        for (int jf = 0; jf < 4; jf++)
            #pragma unroll
            for (int cf = 0; cf < 8; cf++)
                Rb[((jf*8 + cf) << 6) + l] = acc[jf][cf];
    } else if (wv == 3) {
        #pragma unroll
        for (int jf = 0; jf < 4; jf++)
            #pragma unroll
            for (int cf = 0; cf < 8; cf++)
                Rb[2048 + ((jf*8 + cf) << 6) + l] = acc[jf][cf];
    }
    __syncthreads();
    if (wv == 0) {
        #pragma unroll
        for (int jf = 0; jf < 4; jf++)
            #pragma unroll
            for (int cf = 0; cf < 8; cf++)
                acc[jf][cf] += Rb[((jf*8 + cf) << 6) + l];
    } else if (wv == 1) {
        #pragma unroll
        for (int jf = 0; jf < 4; jf++)
            #pragma unroll
            for (int cf = 0; cf < 8; cf++)
                acc[jf][cf] += Rb[2048 + ((jf*8 + cf) << 6) + l];
    }
    __syncthreads();
    if (wv == 0) {          // gives jf {2,3} at base 0, slots {0,1}
        #pragma unroll
        for (int cf = 0; cf < 8; cf++) {
            Rb[((0*8 + cf) << 6) + l] = acc[2][cf];
            Rb[((1*8 + cf) << 6) + l] = acc[3][cf];
        }
    } else if (wv == 1) {   // gives jf {0,1} at base 2048, slots {0,1}
        #pragma unroll
        for (int cf = 0; cf < 8; cf++) {
            Rb[2048 + ((0*8 + cf) << 6) + l] = acc[0][cf];
            Rb[2048 + ((1*8 + cf) << 6) + l] = acc[1][cf];
        }
    }
    __syncthreads();

    const float gam = gamma[0];
    // Final: wv0 outputs jf {0,1} (reads wave1's halves at base 2048);
    //        wv1 outputs jf {2,3} (reads wave0's halves at base 0).
    if (wv == 0) {
        #pragma unroll
        for (int cf = 0; cf < 8; cf++) {
            {   // jf = 0 (wave1 stored at base 2048, slot 0)
                f32x4 o = Rb[2048 + ((0*8 + cf) << 6) + l];
                f32x4 a = acc[0][cf];
                a[0]+=o[0]; a[1]+=o[1]; a[2]+=o[2]; a[3]+=o[3];
                const int c = cbase + cf*16 + lr;
                const int j = jbase + 0*16 + lg*4;
                size_t off = ((size_t)(b*CCH + c))*NN + j;
                float4 xv = *(const float4*)(x + off);
                float4 ov;
                ov.x = fmaf(gam, a[0], xv.x);
                ov.y = fmaf(gam, a[1], xv.y);
                ov.z = fmaf(gam, a[2], xv.z);
                ov.w = fmaf(gam, a[3], xv.w);
                *(float4*)(out + off) = ov;
            }
            {   // jf = 1 (base 2048, slot 1)
                f32x4 o = Rb[2048 + ((1*8 + cf) << 6) + l];
                f32x4 a = acc[1][cf];
                a[0]+=o[0]; a[1]+=o[1]; a[2]+=o[2]; a[3]+=o[3];
                const int c = cbase + cf*16 + lr;
                const int j = jbase + 1*16 + lg*4;
                size_t off = ((size_t)(b*CCH + c))*NN + j;
                float4 xv = *(const float4*)(x + off);
                float4 ov;
                ov.x = fmaf(gam, a[0], xv.x);
                ov.y = fmaf(gam, a[1], xv.y);
                ov.z = fmaf(gam, a[2], xv.z);
                ov.w = fmaf(gam, a[3], xv.w);
                *(float4*)(out + off) = ov;
            }
        }
    } else if (wv == 1) {
        #pragma unroll
        for (int cf = 0; cf < 8; cf++) {
            {   // jf = 2 (wave0 stored at base 0, slot 0)
                f32x4 o = Rb[((0*8 + cf) << 6) + l];
                f32x4 a = acc[2][cf];
                a[0]+=o[0]; a[1]+=o[1]; a[2]+=o[2]; a[3]+=o[3];
                const int c = cbase + cf*16 + lr;
                const int j = jbase + 2*16 + lg*4;
                size_t off = ((size_t)(b*CCH + c))*NN + j;
                float4 xv = *(const float4*)(x + off);
                float4 ov;
                ov.x = fmaf(gam, a[0], xv.x);
                ov.y = fmaf(gam, a[1], xv.y);
                ov.z = fmaf(gam, a[2], xv.z);
                ov.w = fmaf(gam, a[3], xv.w);
                *(float4*)(out + off) = ov;
            }
            {   // jf = 3 (base 0, slot 1)
                f32x4 o = Rb[((1*8 + cf) << 6) + l];
                f32x4 a = acc[3][cf];
                a[0]+=o[0]; a[1]+=o[1]; a[2]+=o[2]; a[3]+=o[3];
                const int c = cbase + cf*16 + lr;
                const int j = jbase + 3*16 + lg*4;
                size_t off = ((size_t)(b*CCH + c))*NN + j;
                float4 xv = *(const float4*)(x + off);
                float4 ov;
                ov.x = fmaf(gam, a[0], xv.x);
                ov.y = fmaf(gam, a[1], xv.y);
                ov.z = fmaf(gam, a[2], xv.z);
                ov.w = fmaf(gam, a[3], xv.w);
                *(float4*)(out + off) = ov;
            }
        }
    }
}

// ---------------------------------------------------------------- launch
extern "C" void kernel_launch(void* const* d_in, const int* in_sizes, int n_in,
                              void* d_out, int out_size, void* d_ws, size_t ws_size,
                              hipStream_t stream)
{
    (void)in_sizes; (void)n_in; (void)out_size; (void)ws_size;
    const float* x     = (const float*)d_in[0];
    const float* wq    = (const float*)d_in[1];
    const float* bq    = (const float*)d_in[2];
    const float* wk    = (const float*)d_in[3];
    const float* bk    = (const float*)d_in[4];
    const float* wv    = (const float*)d_in[5];
    const float* bv    = (const float*)d_in[6];
    const float* gamma = (const float*)d_in[7];
    float* out = (float*)d_out;

    char* ws = (char*)d_ws;
    _Float16* q16  = (_Float16*)(ws + 0x000000);  // 1MB (f16 single)
    _Float16* k_hi = (_Float16*)(ws + 0x100000);  // 1MB (f16 hi)
    _Float16* k_lo = (_Float16*)(ws + 0x200000);  // 1MB (f16 lo)
    _Float16* v16  = (_Float16*)(ws + 0x400000);  // 8MB blocked
    float*    Sx   = (float*)   (ws + 0xC00000);  // 64KB (SL = log2 Z)

    proj_fused  <<<dim3(3, 64, 4), 512, 0, stream>>>(
        x, wq, bq, wk, bk, wv, bv, q16, k_hi, k_lo, v16);
    stats_kernel<<<dim3(64, 4),    512, 0, stream>>>(q16, k_hi, k_lo, Sx);
    attn_kernel <<<dim3(512),      256, 0, stream>>>(
        q16, k_hi, k_lo, v16, Sx, x, gamma, out);
}

// Round 16
// 101.622 us; speedup vs baseline: 1.3034x; 1.3034x over previous
//
#include <hip/hip_runtime.h>

#define NB 4
#define CCH 256
#define NN 4096
#define DD 32

typedef __attribute__((ext_vector_type(8))) short bf16x8;
typedef __attribute__((ext_vector_type(8))) _Float16 f16x8;
typedef __attribute__((ext_vector_type(4))) _Float16 f16x4;
typedef __attribute__((ext_vector_type(2))) __fp16 fp16x2;
typedef __attribute__((ext_vector_type(4))) float f32x4;

#define MFB(a,b,c) __builtin_amdgcn_mfma_f32_16x16x32_bf16(a,b,c,0,0,0)
#define MFH(a,b,c) __builtin_amdgcn_mfma_f32_16x16x32_f16(a,b,c,0,0,0)
#define L2E 1.44269504f

__device__ inline unsigned short f2bf(float f){
    union { float f; unsigned u; } v; v.f = f;
    unsigned r = v.u + 0x7fffu + ((v.u >> 16) & 1u);
    return (unsigned short)(r >> 16);
}
__device__ inline float bfval(unsigned short h){
    union { unsigned u; float f; } v; v.u = ((unsigned)h) << 16; return v.f;
}
// native transcendental: D = 2^S0 (exactly what SL-folded softmax needs)
__device__ inline float vexp2(float x){
    float r; asm("v_exp_f32 %0, %1" : "=v"(r) : "v"(x)); return r;
}
__device__ inline f16x4 pk4(float p0, float p1, float p2, float p3){
    union { fp16x2 h2[2]; f16x4 v; } u;
    u.h2[0] = __builtin_amdgcn_cvt_pkrtz(p0, p1);
    u.h2[1] = __builtin_amdgcn_cvt_pkrtz(p2, p3);
    return u.v;
}

// ---------------------------------------------------------------- prep_w_blk
// R29 (from R28 evidence: proj_fused 65us at MfmaUtil 4.4% / ~65% stall --
// the w-fragment loads are 16B/lane at 1KB stride = ~64 cache lines per
// load instruction, re-issued by all 256 blocks. R27's prep_w failed
// because it kept the row-major layout -> kept the uncoalesced loads).
// Fix: convert w ONCE into MFMA-fragment-BLOCKED layout [tile][kc][lg][lr][8]
// so a wave's fragment load is 1KB CONTIGUOUS.
__global__ __launch_bounds__(256) void prep_w_blk(
    const float* __restrict__ wq, const float* __restrict__ wk,
    const float* __restrict__ wv,
    unsigned short* __restrict__ wqh, unsigned short* __restrict__ wql,
    unsigned short* __restrict__ wkh, unsigned short* __restrict__ wkl,
    unsigned short* __restrict__ wvh, unsigned short* __restrict__ wvl)
{
    const int idx = blockIdx.x*256 + threadIdx.x;   // 0..81919 (grid 320)
    const float* src; unsigned short *dh, *dl; int d, c;
    if (idx < 8192)       { src = wq; dh = wqh; dl = wql; d = idx >> 8;           c = idx & 255; }
    else if (idx < 16384) { src = wk; dh = wkh; dl = wkl; d = (idx-8192) >> 8;    c = idx & 255; }
    else                  { src = wv; dh = wvh; dl = wvl; d = (idx-16384) >> 8;   c = idx & 255; }
    float v = src[d*CCH + c];
    const int tile = d >> 4, lr = d & 15;
    const int kc = c >> 5, lg = (c >> 3) & 3, e = c & 7;
    const int off = ((((tile*8 + kc)*4 + lg)*16) + lr)*8 + e;
    unsigned short h = f2bf(v);
    dh[off] = h;
    dl[off] = f2bf(v - bfval(h));
}

// ---------------------------------------------------------------- proj_qk
// q = single f16; k = f16 hi/lo. w loads now COALESCED blocked fragments.
__global__ __launch_bounds__(256) void proj_qk(
    const float* __restrict__ x,
    const unsigned short* __restrict__ wqh, const unsigned short* __restrict__ wql,
    const float* __restrict__ bq,
    const unsigned short* __restrict__ wkh, const unsigned short* __restrict__ wkl,
    const float* __restrict__ bk,
    _Float16* __restrict__ q16,
    _Float16* __restrict__ k_hi, _Float16* __restrict__ k_lo)
{
    const int t = threadIdx.x;
    const int w = t >> 6;
    const int l = t & 63;
    const int lr = l & 15, lg = l >> 4;
    const int nb = blockIdx.x;
    const int b  = blockIdx.y;
    const int n0 = nb*64 + w*16;
    const int n  = n0 + lr;

    const float* xb = x + (size_t)b*CCH*NN;

    f32x4 acc[4] = {};

    for (int kc = 0; kc < 8; kc++) {
        const int cbase = kc*32 + lg*8;
        float xv[8];
        #pragma unroll
        for (int e = 0; e < 8; e++)
            xv[e] = xb[(size_t)(cbase + e)*NN + n];
        bf16x8 xh, xl;
        #pragma unroll
        for (int e = 0; e < 8; e++) {
            unsigned short h = f2bf(xv[e]);
            xh[e] = (short)h;
            xl[e] = (short)f2bf(xv[e] - bfval(h));
        }
        #pragma unroll
        for (int f = 0; f < 4; f++) {
            const int off = ((((f & 1)*8 + kc)*4 + lg)*16 + lr)*8;
            const unsigned short* ph = (f < 2) ? wqh : wkh;
            const unsigned short* pl = (f < 2) ? wql : wkl;
            bf16x8 wh = *(const bf16x8*)(ph + off);
            bf16x8 wl = *(const bf16x8*)(pl + off);
            acc[f] = MFB(xh, wl, acc[f]);
            acc[f] = MFB(xl, wh, acc[f]);
            acc[f] = MFB(xh, wh, acc[f]);
        }
    }

    #pragma unroll
    for (int f = 0; f < 4; f++) {
        const int d = (f & 1)*16 + lr;
        const bool isq = (f < 2);
        float bias = isq ? bq[d] : bk[d];
        #pragma unroll
        for (int r = 0; r < 4; r++) {
            int nn = n0 + lg*4 + r;
            float val = acc[f][r] + bias;
            size_t a = ((size_t)(b*NN + nn))*DD + d;
            if (isq) {
                q16[a] = (_Float16)val;
            } else {
                _Float16 h = (_Float16)val;
                k_hi[a] = h;
                k_lo[a] = (_Float16)(val - (float)h);
            }
        }
    }
}

// ---------------------------------------------------------------- proj_v
// Output layout BLOCKED: v16[b][ib=n/8][c][8] (f16), 16B per (ib,c) chunk.
// w loads = coalesced blocked fragments (prep_w_blk).
__global__ __launch_bounds__(512) void proj_v(
    const float* __restrict__ x,
    const unsigned short* __restrict__ wvh, const unsigned short* __restrict__ wvl,
    const float* __restrict__ bv,
    _Float16* __restrict__ v16)
{
    const int t = threadIdx.x;
    const int w = t >> 6;
    const int cg = w >> 2;
    const int ng = w & 3;
    const int l = t & 63;
    const int lr = l & 15, lg = l >> 4;
    const int ob = blockIdx.x;
    const int nb = blockIdx.y;
    const int b  = blockIdx.z;
    const int n0 = nb*64 + ng*16;
    const int n  = n0 + lr;
    const int cbase0 = ob*128 + cg*64;
    const int ctile0 = ob*8 + cg*4;

    const float* xb = x + (size_t)b*CCH*NN;

    f32x4 acc[4] = {};

    for (int kc = 0; kc < 8; kc++) {
        const int kbase = kc*32 + lg*8;
        float xv[8];
        #pragma unroll
        for (int e = 0; e < 8; e++)
            xv[e] = xb[(size_t)(kbase + e)*NN + n];
        bf16x8 xh, xl;
        #pragma unroll
        for (int e = 0; e < 8; e++) {
            unsigned short h = f2bf(xv[e]);
            xh[e] = (short)h;
            xl[e] = (short)f2bf(xv[e] - bfval(h));
        }
        #pragma unroll
        for (int f = 0; f < 4; f++) {
            const int off = ((((ctile0 + f)*8 + kc)*4 + lg)*16 + lr)*8;
            bf16x8 wh = *(const bf16x8*)(wvh + off);
            bf16x8 wl = *(const bf16x8*)(wvl + off);
            acc[f] = MFB(wl, xh, acc[f]);
            acc[f] = MFB(wh, xl, acc[f]);
            acc[f] = MFB(wh, xh, acc[f]);
        }
    }

    const size_t bslice = (size_t)b*(NN/8);
    #pragma unroll
    for (int f = 0; f < 4; f++) {
        #pragma unroll
        for (int r = 0; r < 4; r++) {
            int c = cbase0 + f*16 + lg*4 + r;
            float val = acc[f][r] + bv[c];
            v16[(((bslice + (n >> 3))*CCH + c) << 3) + (n & 7)] = (_Float16)val;
        }
    }
}

// ---------------------------------------------------------------- stats
// combine fused (writes Sx = log2 Z directly); i-tile 32 with grid (128,4)
// restores R26's block parallelism (512 blocks).
__global__ __launch_bounds__(512) void stats_kernel(
    const _Float16* __restrict__ q16,
    const _Float16* __restrict__ kh, const _Float16* __restrict__ kl,
    float* __restrict__ Sx)
{
    __shared__ float zW[8][32];
    const int t = threadIdx.x;
    const int w = t >> 6;
    const int l = t & 63;
    const int lr = l & 15, lg = l >> 4;
    const int it = blockIdx.x;   // 0..127 : i-tile (32 rows each)
    const int b  = blockIdx.y;
    const int ibase = it*32;
    const f32x4 zero = {0.f,0.f,0.f,0.f};

    f16x8 qf[2];
    #pragma unroll
    for (int f = 0; f < 2; f++) {
        size_t a = ((size_t)(b*NN + ibase + f*16 + lr))*DD + lg*8;
        qf[f] = *(const f16x8*)(q16 + a);
    }
    float Z[2] = {0.f, 0.f};

    const size_t k0 = ((size_t)(b*NN + w*16 + lr))*DD + lg*8;
    const _Float16* kp  = kh + k0;
    const _Float16* klp = kl + k0;

    for (int jt = 0; jt < 32; ++jt) {
        f16x8 kh2 = *(const f16x8*)kp;
        f16x8 kl2 = *(const f16x8*)klp;
        #pragma unroll
        for (int f = 0; f < 2; f++) {
            f32x4 e = MFH(kl2, qf[f], zero);
            e = MFH(kh2, qf[f], e);
            Z[f] += vexp2(e[0]*L2E) + vexp2(e[1]*L2E)
                  + vexp2(e[2]*L2E) + vexp2(e[3]*L2E);
        }
        kp  += 128*DD;
        klp += 128*DD;
    }
    #pragma unroll
    for (int f = 0; f < 2; f++) {
        Z[f] += __shfl_xor(Z[f], 16, 64);
        Z[f] += __shfl_xor(Z[f], 32, 64);
        if (lg == 0) zW[w][f*16 + lr] = Z[f];
    }
    __syncthreads();
    if (t < 32) {
        float z = 0.f;
        #pragma unroll
        for (int w2 = 0; w2 < 8; ++w2) z += zW[w2][t];
        Sx[(size_t)b*NN + ibase + t] = log2f(z);
    }
}

// ---------------------------------------------------------------- attn
// R27(a), unchanged (attn ~57.5us, MFMA busy 21.8us ~ full-rate floor):
// sigma-permuted q rows -> K=32 full-rate PV with zero shuffles;
// phase-split step (all 4 jf QK+exp first, then ONE un-fenced PV cluster).
__global__ __launch_bounds__(256, 2) void attn_kernel(
    const _Float16* __restrict__ q16,
    const _Float16* __restrict__ kh16, const _Float16* __restrict__ kl16,
    const _Float16* __restrict__ v16,
    const float* __restrict__ Sx,
    const float* __restrict__ x, const float* __restrict__ gamma,
    float* __restrict__ out)
{
    __shared__ __align__(16) f32x4 Rb[4096];   // 64KB end-reduce buffer

    const int t = threadIdx.x;
    const int wv = t >> 6;       // i-quarter 0..3
    const int l = t & 63;
    const int lr = l & 15, lg = l >> 4;

    // XCD slice: lin&7 = (b,ct) -> one slice per XCD (~1.8MB, L2-resident).
    const int lin = blockIdx.x;
    const int slice = lin & 7;
    const int b   = slice >> 1;
    const int ct  = slice & 1;
    const int jt  = lin >> 3;    // 0..63
    const int jbase = jt*64, cbase = ct*128;

    // K B-fragments: 4 j-frags, f16 hi/lo (persistent; 32 VGPR)
    f16x8 kfh[4], kfl[4];
    #pragma unroll
    for (int jf = 0; jf < 4; jf++) {
        size_t a = ((size_t)(b*NN + jbase + jf*16 + lr))*DD + lg*8;
        kfh[jf] = *(const f16x8*)(kh16 + a);
        kfl[jf] = *(const f16x8*)(kl16 + a);
    }

    const float* Sb = Sx + (size_t)b*NN;
    const _Float16* vb = v16 + (size_t)b*(NN/8)*CCH*8;

    const int i0 = wv*1024;     // this wave's i-quarter; 32 steps of 32

    // sigma-permuted q pointers: step A rows 8(lr>>2)+(lr&3), step B +4
    const int sigma = 8*(lr >> 2) + (lr & 3);
    const _Float16* qpA = q16 + ((size_t)(b*NN + i0 + sigma))*DD + lg*8;
    const _Float16* qpB = qpA + 4*DD;
    // s pointers follow sigma: lane lg covers i = 8lg+r (A), 8lg+4+r (B)
    const float* spA = Sb + i0 + 8*lg;
    const float* spB = spA + 4;
    // V B-frag: lane (lr,lg) reads 16B block ib = i0/8 + lg, c = ..+lr
    const _Float16* vp = vb + (((size_t)(i0/8 + lg)*CCH + cbase + lr) << 3);

    f32x4 acc[4][8] = {};   // [jf][cf] -- ONLY static subscripts below!

    #pragma clang loop unroll(disable)
    for (int s = 0; s < 32; ++s) {
        // loads for THIS step (L2-resident; TLP hides the latency)
        f16x8 qA = *(const f16x8*)qpA;  qpA += 32*DD;
        f16x8 qB = *(const f16x8*)qpB;  qpB += 32*DD;
        float4 sA4 = *(const float4*)spA; spA += 32;
        float4 sB4 = *(const float4*)spB; spB += 32;
        f16x8 vv[8];
        #pragma unroll
        for (int cf = 0; cf < 8; cf++)
            vv[cf] = *(const f16x8*)(vp + cf*128);
        vp += 32*CCH;

        // ---- Phase 1: all 4 jf QK + exp + pack (independent chains) ----
        f16x8 pa[4];
        #pragma unroll
        for (int jf = 0; jf < 4; jf++) {
            f32x4 eA = {};
            eA = MFH(qA, kfl[jf], eA);
            eA = MFH(qA, kfh[jf], eA);
            f32x4 eB = {};
            eB = MFH(qB, kfl[jf], eB);
            eB = MFH(qB, kfh[jf], eB);
            union { f16x4 h4[2]; f16x8 h8; } pu;
            pu.h4[0] = pk4(vexp2(fmaf(eA[0], L2E, -sA4.x)),
                           vexp2(fmaf(eA[1], L2E, -sA4.y)),
                           vexp2(fmaf(eA[2], L2E, -sA4.z)),
                           vexp2(fmaf(eA[3], L2E, -sA4.w)));
            pu.h4[1] = pk4(vexp2(fmaf(eB[0], L2E, -sB4.x)),
                           vexp2(fmaf(eB[1], L2E, -sB4.y)),
                           vexp2(fmaf(eB[2], L2E, -sB4.z)),
                           vexp2(fmaf(eB[3], L2E, -sB4.w)));
            pa[jf] = pu.h8;
        }

        // ---- Phase 2: ONE un-fenced PV cluster (32 full-rate MFH) ----
        __builtin_amdgcn_s_setprio(1);
        #pragma unroll
        for (int jf = 0; jf < 4; jf++)
            #pragma unroll
            for (int cf = 0; cf < 8; cf++)
                acc[jf][cf] = MFH(pa[jf], vv[cf], acc[jf][cf]);
        __builtin_amdgcn_s_setprio(0);
    }

    // ------------- 3-barrier tree reduce over the 4 i-quarters -------------
    // All acc subscripts literal. slot(jf,cf) = (jf*8+cf)<<6 | lane.
    if (wv == 2) {
        #pragma unroll
        for (int jf = 0; jf < 4; jf++)
            #pragma unroll
            for (int cf = 0; cf < 8; cf++)
                Rb[((jf*8 + cf) << 6) + l] = acc[jf][cf];
    } else if (wv == 3) {
        #pragma unroll
        for (int jf = 0; jf < 4; jf++)
            #pragma unroll
            for (int cf = 0; cf < 8; cf++)
                Rb[2048 + ((jf*8 + cf) << 6) + l] = acc[jf][cf];
    }
    __syncthreads();
    if (wv == 0) {
        #pragma unroll
        for (int jf = 0; jf < 4; jf++)
            #pragma unroll
            for (int cf = 0; cf < 8; cf++)
                acc[jf][cf] += Rb[((jf*8 + cf) << 6) + l];
    } else if (wv == 1) {
        #pragma unroll
        for (int jf = 0; jf < 4; jf++)
            #pragma unroll
            for (int cf = 0; cf < 8; cf++)
                acc[jf][cf] += Rb[2048 + ((jf*8 + cf) << 6) + l];
    }
    __syncthreads();
    if (wv == 0) {          // gives jf {2,3} at base 0, slots {0,1}
        #pragma unroll
        for (int cf = 0; cf < 8; cf++) {
            Rb[((0*8 + cf) << 6) + l] = acc[2][cf];
            Rb[((1*8 + cf) << 6) + l] = acc[3][cf];
        }
    } else if (wv == 1) {   // gives jf {0,1} at base 2048, slots {0,1}
        #pragma unroll
        for (int cf = 0; cf < 8; cf++) {
            Rb[2048 + ((0*8 + cf) << 6) + l] = acc[0][cf];
            Rb[2048 + ((1*8 + cf) << 6) + l] = acc[1][cf];
        }
    }
    __syncthreads();

    const float gam = gamma[0];
    // Final: wv0 outputs jf {0,1} (reads wave1's halves at base 2048);
    //        wv1 outputs jf {2,3} (reads wave0's halves at base 0).
    if (wv == 0) {
        #pragma unroll
        for (int cf = 0; cf < 8; cf++) {
            {   // jf = 0 (wave1 stored at base 2048, slot 0)
                f32x4 o = Rb[2048 + ((0*8 + cf) << 6) + l];
                f32x4 a = acc[0][cf];
                a[0]+=o[0]; a[1]+=o[1]; a[2]+=o[2]; a[3]+=o[3];
                const int c = cbase + cf*16 + lr;
                const int j = jbase + 0*16 + lg*4;
                size_t off = ((size_t)(b*CCH + c))*NN + j;
                float4 xv = *(const float4*)(x + off);
                float4 ov;
                ov.x = fmaf(gam, a[0], xv.x);
                ov.y = fmaf(gam, a[1], xv.y);
                ov.z = fmaf(gam, a[2], xv.z);
                ov.w = fmaf(gam, a[3], xv.w);
                *(float4*)(out + off) = ov;
            }
            {   // jf = 1 (base 2048, slot 1)
                f32x4 o = Rb[2048 + ((1*8 + cf) << 6) + l];
                f32x4 a = acc[1][cf];
                a[0]+=o[0]; a[1]+=o[1]; a[2]+=o[2]; a[3]+=o[3];
                const int c = cbase + cf*16 + lr;
                const int j = jbase + 1*16 + lg*4;
                size_t off = ((size_t)(b*CCH + c))*NN + j;
                float4 xv = *(const float4*)(x + off);
                float4 ov;
                ov.x = fmaf(gam, a[0], xv.x);
                ov.y = fmaf(gam, a[1], xv.y);
                ov.z = fmaf(gam, a[2], xv.z);
                ov.w = fmaf(gam, a[3], xv.w);
                *(float4*)(out + off) = ov;
            }
        }
    } else if (wv == 1) {
        #pragma unroll
        for (int cf = 0; cf < 8; cf++) {
            {   // jf = 2 (wave0 stored at base 0, slot 0)
                f32x4 o = Rb[((0*8 + cf) << 6) + l];
                f32x4 a = acc[2][cf];
                a[0]+=o[0]; a[1]+=o[1]; a[2]+=o[2]; a[3]+=o[3];
                const int c = cbase + cf*16 + lr;
                const int j = jbase + 2*16 + lg*4;
                size_t off = ((size_t)(b*CCH + c))*NN + j;
                float4 xv = *(const float4*)(x + off);
                float4 ov;
                ov.x = fmaf(gam, a[0], xv.x);
                ov.y = fmaf(gam, a[1], xv.y);
                ov.z = fmaf(gam, a[2], xv.z);
                ov.w = fmaf(gam, a[3], xv.w);
                *(float4*)(out + off) = ov;
            }
            {   // jf = 3 (base 0, slot 1)
                f32x4 o = Rb[((1*8 + cf) << 6) + l];
                f32x4 a = acc[3][cf];
                a[0]+=o[0]; a[1]+=o[1]; a[2]+=o[2]; a[3]+=o[3];
                const int c = cbase + cf*16 + lr;
                const int j = jbase + 3*16 + lg*4;
                size_t off = ((size_t)(b*CCH + c))*NN + j;
                float4 xv = *(const float4*)(x + off);
                float4 ov;
                ov.x = fmaf(gam, a[0], xv.x);
                ov.y = fmaf(gam, a[1], xv.y);
                ov.z = fmaf(gam, a[2], xv.z);
                ov.w = fmaf(gam, a[3], xv.w);
                *(float4*)(out + off) = ov;
            }
        }
    }
}

// ---------------------------------------------------------------- launch
extern "C" void kernel_launch(void* const* d_in, const int* in_sizes, int n_in,
                              void* d_out, int out_size, void* d_ws, size_t ws_size,
                              hipStream_t stream)
{
    (void)in_sizes; (void)n_in; (void)out_size; (void)ws_size;
    const float* x     = (const float*)d_in[0];
    const float* wq    = (const float*)d_in[1];
    const float* bq    = (const float*)d_in[2];
    const float* wk    = (const float*)d_in[3];
    const float* bk    = (const float*)d_in[4];
    const float* wv    = (const float*)d_in[5];
    const float* bv    = (const float*)d_in[6];
    const float* gamma = (const float*)d_in[7];
    float* out = (float*)d_out;

    char* ws = (char*)d_ws;
    _Float16* q16  = (_Float16*)(ws + 0x000000);  // 1MB (f16 single)
    _Float16* k_hi = (_Float16*)(ws + 0x100000);  // 1MB (f16 hi)
    _Float16* k_lo = (_Float16*)(ws + 0x200000);  // 1MB (f16 lo)
    _Float16* v16  = (_Float16*)(ws + 0x400000);  // 8MB blocked
    float*    Sx   = (float*)   (ws + 0xC00000);  // 64KB (SL = log2 Z)
    unsigned short* wqh = (unsigned short*)(ws + 0xC10000);  // 16KB blocked
    unsigned short* wql = (unsigned short*)(ws + 0xC14000);  // 16KB
    unsigned short* wkh = (unsigned short*)(ws + 0xC18000);  // 16KB
    unsigned short* wkl = (unsigned short*)(ws + 0xC1C000);  // 16KB
    unsigned short* wvh = (unsigned short*)(ws + 0xC20000);  // 128KB
    unsigned short* wvl = (unsigned short*)(ws + 0xC40000);  // 128KB

    prep_w_blk  <<<dim3(320),      256, 0, stream>>>(
        wq, wk, wv, wqh, wql, wkh, wkl, wvh, wvl);
    proj_qk     <<<dim3(64, 4),    256, 0, stream>>>(
        x, wqh, wql, bq, wkh, wkl, bk, q16, k_hi, k_lo);
    proj_v      <<<dim3(2, 64, 4), 512, 0, stream>>>(x, wvh, wvl, bv, v16);
    stats_kernel<<<dim3(128, 4),   512, 0, stream>>>(q16, k_hi, k_lo, Sx);
    attn_kernel <<<dim3(512),      256, 0, stream>>>(
        q16, k_hi, k_lo, v16, Sx, x, gamma, out);
}

// Round 17
// 101.271 us; speedup vs baseline: 1.3079x; 1.0035x over previous
//
#include <hip/hip_runtime.h>

#define NB 4
#define CCH 256
#define NN 4096
#define DD 32

typedef __attribute__((ext_vector_type(8))) short bf16x8;
typedef __attribute__((ext_vector_type(8))) _Float16 f16x8;
typedef __attribute__((ext_vector_type(4))) _Float16 f16x4;
typedef __attribute__((ext_vector_type(2))) __fp16 fp16x2;
typedef __attribute__((ext_vector_type(4))) float f32x4;

#define MFB(a,b,c) __builtin_amdgcn_mfma_f32_16x16x32_bf16(a,b,c,0,0,0)
#define MFH(a,b,c) __builtin_amdgcn_mfma_f32_16x16x32_f16(a,b,c,0,0,0)
#define L2E 1.44269504f

__device__ inline unsigned short f2bf(float f){
    union { float f; unsigned u; } v; v.f = f;
    unsigned r = v.u + 0x7fffu + ((v.u >> 16) & 1u);
    return (unsigned short)(r >> 16);
}
__device__ inline float bfval(unsigned short h){
    union { unsigned u; float f; } v; v.u = ((unsigned)h) << 16; return v.f;
}
// native transcendental: D = 2^S0 (exactly what SL-folded softmax needs)
__device__ inline float vexp2(float x){
    float r; asm("v_exp_f32 %0, %1" : "=v"(r) : "v"(x)); return r;
}
__device__ inline f16x4 pk4(float p0, float p1, float p2, float p3){
    union { fp16x2 h2[2]; f16x4 v; } u;
    u.h2[0] = __builtin_amdgcn_cvt_pkrtz(p0, p1);
    u.h2[1] = __builtin_amdgcn_cvt_pkrtz(p2, p3);
    return u.v;
}

// ---------------------------------------------------------------- prep_w_blk
// Convert w ONCE into MFMA-fragment-BLOCKED layout [tile][kc][lg][lr][8]
// so a wave's fragment load is 1KB CONTIGUOUS (R29: proj 65us -> fixed;
// R28 evidence was MfmaUtil 4.4% from 1KB-stride 16B loads x256 blocks).
__global__ __launch_bounds__(256) void prep_w_blk(
    const float* __restrict__ wq, const float* __restrict__ wk,
    const float* __restrict__ wv,
    unsigned short* __restrict__ wqh, unsigned short* __restrict__ wql,
    unsigned short* __restrict__ wkh, unsigned short* __restrict__ wkl,
    unsigned short* __restrict__ wvh, unsigned short* __restrict__ wvl)
{
    const int idx = blockIdx.x*256 + threadIdx.x;   // 0..81919 (grid 320)
    const float* src; unsigned short *dh, *dl; int d, c;
    if (idx < 8192)       { src = wq; dh = wqh; dl = wql; d = idx >> 8;           c = idx & 255; }
    else if (idx < 16384) { src = wk; dh = wkh; dl = wkl; d = (idx-8192) >> 8;    c = idx & 255; }
    else                  { src = wv; dh = wvh; dl = wvl; d = (idx-16384) >> 8;   c = idx & 255; }
    float v = src[d*CCH + c];
    const int tile = d >> 4, lr = d & 15;
    const int kc = c >> 5, lg = (c >> 3) & 3, e = c & 7;
    const int off = ((((tile*8 + kc)*4 + lg)*16) + lr)*8 + e;
    unsigned short h = f2bf(v);
    dh[off] = h;
    dl[off] = f2bf(v - bfval(h));
}

// ---------------------------------------------------------------- proj_qk
// q = single f16; k = f16 hi/lo. w loads COALESCED blocked fragments.
__global__ __launch_bounds__(256) void proj_qk(
    const float* __restrict__ x,
    const unsigned short* __restrict__ wqh, const unsigned short* __restrict__ wql,
    const float* __restrict__ bq,
    const unsigned short* __restrict__ wkh, const unsigned short* __restrict__ wkl,
    const float* __restrict__ bk,
    _Float16* __restrict__ q16,
    _Float16* __restrict__ k_hi, _Float16* __restrict__ k_lo)
{
    const int t = threadIdx.x;
    const int w = t >> 6;
    const int l = t & 63;
    const int lr = l & 15, lg = l >> 4;
    const int nb = blockIdx.x;
    const int b  = blockIdx.y;
    const int n0 = nb*64 + w*16;
    const int n  = n0 + lr;

    const float* xb = x + (size_t)b*CCH*NN;

    f32x4 acc[4] = {};

    for (int kc = 0; kc < 8; kc++) {
        const int cbase = kc*32 + lg*8;
        float xv[8];
        #pragma unroll
        for (int e = 0; e < 8; e++)
            xv[e] = xb[(size_t)(cbase + e)*NN + n];
        bf16x8 xh, xl;
        #pragma unroll
        for (int e = 0; e < 8; e++) {
            unsigned short h = f2bf(xv[e]);
            xh[e] = (short)h;
            xl[e] = (short)f2bf(xv[e] - bfval(h));
        }
        #pragma unroll
        for (int f = 0; f < 4; f++) {
            const int off = ((((f & 1)*8 + kc)*4 + lg)*16 + lr)*8;
            const unsigned short* ph = (f < 2) ? wqh : wkh;
            const unsigned short* pl = (f < 2) ? wql : wkl;
            bf16x8 wh = *(const bf16x8*)(ph + off);
            bf16x8 wl = *(const bf16x8*)(pl + off);
            acc[f] = MFB(xh, wl, acc[f]);
            acc[f] = MFB(xl, wh, acc[f]);
            acc[f] = MFB(xh, wh, acc[f]);
        }
    }

    #pragma unroll
    for (int f = 0; f < 4; f++) {
        const int d = (f & 1)*16 + lr;
        const bool isq = (f < 2);
        float bias = isq ? bq[d] : bk[d];
        #pragma unroll
        for (int r = 0; r < 4; r++) {
            int nn = n0 + lg*4 + r;
            float val = acc[f][r] + bias;
            size_t a = ((size_t)(b*NN + nn))*DD + d;
            if (isq) {
                q16[a] = (_Float16)val;
            } else {
                _Float16 h = (_Float16)val;
                k_hi[a] = h;
                k_lo[a] = (_Float16)(val - (float)h);
            }
        }
    }
}

// ---------------------------------------------------------------- proj_v
// Output layout BLOCKED: v16[b][ib=n/8][c][8] (f16), 16B per (ib,c) chunk.
// w loads = coalesced blocked fragments (prep_w_blk).
__global__ __launch_bounds__(512) void proj_v(
    const float* __restrict__ x,
    const unsigned short* __restrict__ wvh, const unsigned short* __restrict__ wvl,
    const float* __restrict__ bv,
    _Float16* __restrict__ v16)
{
    const int t = threadIdx.x;
    const int w = t >> 6;
    const int cg = w >> 2;
    const int ng = w & 3;
    const int l = t & 63;
    const int lr = l & 15, lg = l >> 4;
    const int ob = blockIdx.x;
    const int nb = blockIdx.y;
    const int b  = blockIdx.z;
    const int n0 = nb*64 + ng*16;
    const int n  = n0 + lr;
    const int cbase0 = ob*128 + cg*64;
    const int ctile0 = ob*8 + cg*4;

    const float* xb = x + (size_t)b*CCH*NN;

    f32x4 acc[4] = {};

    for (int kc = 0; kc < 8; kc++) {
        const int kbase = kc*32 + lg*8;
        float xv[8];
        #pragma unroll
        for (int e = 0; e < 8; e++)
            xv[e] = xb[(size_t)(kbase + e)*NN + n];
        bf16x8 xh, xl;
        #pragma unroll
        for (int e = 0; e < 8; e++) {
            unsigned short h = f2bf(xv[e]);
            xh[e] = (short)h;
            xl[e] = (short)f2bf(xv[e] - bfval(h));
        }
        #pragma unroll
        for (int f = 0; f < 4; f++) {
            const int off = ((((ctile0 + f)*8 + kc)*4 + lg)*16 + lr)*8;
            bf16x8 wh = *(const bf16x8*)(wvh + off);
            bf16x8 wl = *(const bf16x8*)(wvl + off);
            acc[f] = MFB(wl, xh, acc[f]);
            acc[f] = MFB(wh, xl, acc[f]);
            acc[f] = MFB(wh, xh, acc[f]);
        }
    }

    const size_t bslice = (size_t)b*(NN/8);
    #pragma unroll
    for (int f = 0; f < 4; f++) {
        #pragma unroll
        for (int r = 0; r < 4; r++) {
            int c = cbase0 + f*16 + lg*4 + r;
            float val = acc[f][r] + bv[c];
            v16[(((bslice + (n >> 3))*CCH + c) << 3) + (n & 7)] = (_Float16)val;
        }
    }
}

// ---------------------------------------------------------------- stats
// combine fused (writes Sx = log2 Z directly); grid (128,4), i-tile 32.
__global__ __launch_bounds__(512) void stats_kernel(
    const _Float16* __restrict__ q16,
    const _Float16* __restrict__ kh, const _Float16* __restrict__ kl,
    float* __restrict__ Sx)
{
    __shared__ float zW[8][32];
    const int t = threadIdx.x;
    const int w = t >> 6;
    const int l = t & 63;
    const int lr = l & 15, lg = l >> 4;
    const int it = blockIdx.x;   // 0..127 : i-tile (32 rows each)
    const int b  = blockIdx.y;
    const int ibase = it*32;
    const f32x4 zero = {0.f,0.f,0.f,0.f};

    f16x8 qf[2];
    #pragma unroll
    for (int f = 0; f < 2; f++) {
        size_t a = ((size_t)(b*NN + ibase + f*16 + lr))*DD + lg*8;
        qf[f] = *(const f16x8*)(q16 + a);
    }
    float Z[2] = {0.f, 0.f};

    const size_t k0 = ((size_t)(b*NN + w*16 + lr))*DD + lg*8;
    const _Float16* kp  = kh + k0;
    const _Float16* klp = kl + k0;

    for (int jt = 0; jt < 32; ++jt) {
        f16x8 kh2 = *(const f16x8*)kp;
        f16x8 kl2 = *(const f16x8*)klp;
        #pragma unroll
        for (int f = 0; f < 2; f++) {
            f32x4 e = MFH(kl2, qf[f], zero);
            e = MFH(kh2, qf[f], e);
            Z[f] += vexp2(e[0]*L2E) + vexp2(e[1]*L2E)
                  + vexp2(e[2]*L2E) + vexp2(e[3]*L2E);
        }
        kp  += 128*DD;
        klp += 128*DD;
    }
    #pragma unroll
    for (int f = 0; f < 2; f++) {
        Z[f] += __shfl_xor(Z[f], 16, 64);
        Z[f] += __shfl_xor(Z[f], 32, 64);
        if (lg == 0) zW[w][f*16 + lr] = Z[f];
    }
    __syncthreads();
    if (t < 32) {
        float z = 0.f;
        #pragma unroll
        for (int w2 = 0; w2 < 8; ++w2) z += zW[w2][t];
        Sx[(size_t)b*NN + ibase + t] = log2f(z);
    }
}

// ---------------------------------------------------------------- attn
// R30 (from R29 evidence: attn occupancy 16.9% -- the 64KB Rb epilogue
// buffer caps residency at 2 blocks/CU for the WHOLE kernel while VGPR
// (128) would allow 4 waves/SIMD. LDS, not regs, is the limiter).
// Change: end-reduce restructured to 32KB by serializing the donor waves
// through one buffer (A: wv2->Rb, wv0 adds; B: wv3->Rb, wv1 adds;
// C: 16KB+16KB jf-half exchange; D: out). 5 barriers, epilogue-only.
// -> 4 blocks/CU = 4 waves/SIMD at UNCHANGED per-wave work and traffic
// (the clean TLP test R24/R25 confounded). Main loop = R27(a) verbatim.
__global__ __launch_bounds__(256, 2) void attn_kernel(
    const _Float16* __restrict__ q16,
    const _Float16* __restrict__ kh16, const _Float16* __restrict__ kl16,
    const _Float16* __restrict__ v16,
    const float* __restrict__ Sx,
    const float* __restrict__ x, const float* __restrict__ gamma,
    float* __restrict__ out)
{
    __shared__ __align__(16) f32x4 Rb[2048];   // 32KB end-reduce buffer

    const int t = threadIdx.x;
    const int wv = t >> 6;       // i-quarter 0..3
    const int l = t & 63;
    const int lr = l & 15, lg = l >> 4;

    // XCD slice: lin&7 = (b,ct) -> one slice per XCD (~1.8MB, L2-resident).
    const int lin = blockIdx.x;
    const int slice = lin & 7;
    const int b   = slice >> 1;
    const int ct  = slice & 1;
    const int jt  = lin >> 3;    // 0..63
    const int jbase = jt*64, cbase = ct*128;

    // K B-fragments: 4 j-frags, f16 hi/lo (persistent; 32 VGPR)
    f16x8 kfh[4], kfl[4];
    #pragma unroll
    for (int jf = 0; jf < 4; jf++) {
        size_t a = ((size_t)(b*NN + jbase + jf*16 + lr))*DD + lg*8;
        kfh[jf] = *(const f16x8*)(kh16 + a);
        kfl[jf] = *(const f16x8*)(kl16 + a);
    }

    const float* Sb = Sx + (size_t)b*NN;
    const _Float16* vb = v16 + (size_t)b*(NN/8)*CCH*8;

    const int i0 = wv*1024;     // this wave's i-quarter; 32 steps of 32

    // sigma-permuted q pointers: step A rows 8(lr>>2)+(lr&3), step B +4
    const int sigma = 8*(lr >> 2) + (lr & 3);
    const _Float16* qpA = q16 + ((size_t)(b*NN + i0 + sigma))*DD + lg*8;
    const _Float16* qpB = qpA + 4*DD;
    // s pointers follow sigma: lane lg covers i = 8lg+r (A), 8lg+4+r (B)
    const float* spA = Sb + i0 + 8*lg;
    const float* spB = spA + 4;
    // V B-frag: lane (lr,lg) reads 16B block ib = i0/8 + lg, c = ..+lr
    const _Float16* vp = vb + (((size_t)(i0/8 + lg)*CCH + cbase + lr) << 3);

    f32x4 acc[4][8] = {};   // [jf][cf] -- ONLY static subscripts below!

    #pragma clang loop unroll(disable)
    for (int s = 0; s < 32; ++s) {
        // loads for THIS step (L2-resident; TLP hides the latency)
        f16x8 qA = *(const f16x8*)qpA;  qpA += 32*DD;
        f16x8 qB = *(const f16x8*)qpB;  qpB += 32*DD;
        float4 sA4 = *(const float4*)spA; spA += 32;
        float4 sB4 = *(const float4*)spB; spB += 32;
        f16x8 vv[8];
        #pragma unroll
        for (int cf = 0; cf < 8; cf++)
            vv[cf] = *(const f16x8*)(vp + cf*128);
        vp += 32*CCH;

        // ---- Phase 1: all 4 jf QK + exp + pack (independent chains) ----
        f16x8 pa[4];
        #pragma unroll
        for (int jf = 0; jf < 4; jf++) {
            f32x4 eA = {};
            eA = MFH(qA, kfl[jf], eA);
            eA = MFH(qA, kfh[jf], eA);
            f32x4 eB = {};
            eB = MFH(qB, kfl[jf], eB);
            eB = MFH(qB, kfh[jf], eB);
            union { f16x4 h4[2]; f16x8 h8; } pu;
            pu.h4[0] = pk4(vexp2(fmaf(eA[0], L2E, -sA4.x)),
                           vexp2(fmaf(eA[1], L2E, -sA4.y)),
                           vexp2(fmaf(eA[2], L2E, -sA4.z)),
                           vexp2(fmaf(eA[3], L2E, -sA4.w)));
            pu.h4[1] = pk4(vexp2(fmaf(eB[0], L2E, -sB4.x)),
                           vexp2(fmaf(eB[1], L2E, -sB4.y)),
                           vexp2(fmaf(eB[2], L2E, -sB4.z)),
                           vexp2(fmaf(eB[3], L2E, -sB4.w)));
            pa[jf] = pu.h8;
        }

        // ---- Phase 2: ONE un-fenced PV cluster (32 full-rate MFH) ----
        __builtin_amdgcn_s_setprio(1);
        #pragma unroll
        for (int jf = 0; jf < 4; jf++)
            #pragma unroll
            for (int cf = 0; cf < 8; cf++)
                acc[jf][cf] = MFH(pa[jf], vv[cf], acc[jf][cf]);
        __builtin_amdgcn_s_setprio(0);
    }

    // --------- 32KB sequential reduce over the 4 i-quarters ---------
    // slot(jf,cf) = (jf*8+cf)<<6 | lane.  All acc subscripts literal.
    // Phase A: wv2 dumps; wv0 accumulates.
    if (wv == 2) {
        #pragma unroll
        for (int jf = 0; jf < 4; jf++)
            #pragma unroll
            for (int cf = 0; cf < 8; cf++)
                Rb[((jf*8 + cf) << 6) + l] = acc[jf][cf];
    }
    __syncthreads();
    if (wv == 0) {
        #pragma unroll
        for (int jf = 0; jf < 4; jf++)
            #pragma unroll
            for (int cf = 0; cf < 8; cf++)
                acc[jf][cf] += Rb[((jf*8 + cf) << 6) + l];
    }
    __syncthreads();
    // Phase B: wv3 dumps; wv1 accumulates.
    if (wv == 3) {
        #pragma unroll
        for (int jf = 0; jf < 4; jf++)
            #pragma unroll
            for (int cf = 0; cf < 8; cf++)
                Rb[((jf*8 + cf) << 6) + l] = acc[jf][cf];
    }
    __syncthreads();
    if (wv == 1) {
        #pragma unroll
        for (int jf = 0; jf < 4; jf++)
            #pragma unroll
            for (int cf = 0; cf < 8; cf++)
                acc[jf][cf] += Rb[((jf*8 + cf) << 6) + l];
    }
    __syncthreads();
    // Phase C: jf-half exchange. wv0 gives jf{2,3} at base 0 (slots 0,1);
    //          wv1 gives jf{0,1} at base 1024 (slots 0,1).
    if (wv == 0) {
        #pragma unroll
        for (int cf = 0; cf < 8; cf++) {
            Rb[((0*8 + cf) << 6) + l] = acc[2][cf];
            Rb[((1*8 + cf) << 6) + l] = acc[3][cf];
        }
    } else if (wv == 1) {
        #pragma unroll
        for (int cf = 0; cf < 8; cf++) {
            Rb[1024 + ((0*8 + cf) << 6) + l] = acc[0][cf];
            Rb[1024 + ((1*8 + cf) << 6) + l] = acc[1][cf];
        }
    }
    __syncthreads();

    const float gam = gamma[0];
    // Phase D: wv0 outputs jf {0,1} (+ wave1's at base 1024);
    //          wv1 outputs jf {2,3} (+ wave0's at base 0).
    if (wv == 0) {
        #pragma unroll
        for (int cf = 0; cf < 8; cf++) {
            {   // jf = 0 (wave1 slot 0, base 1024)
                f32x4 o = Rb[1024 + ((0*8 + cf) << 6) + l];
                f32x4 a = acc[0][cf];
                a[0]+=o[0]; a[1]+=o[1]; a[2]+=o[2]; a[3]+=o[3];
                const int c = cbase + cf*16 + lr;
                const int j = jbase + 0*16 + lg*4;
                size_t off = ((size_t)(b*CCH + c))*NN + j;
                float4 xv = *(const float4*)(x + off);
                float4 ov;
                ov.x = fmaf(gam, a[0], xv.x);
                ov.y = fmaf(gam, a[1], xv.y);
                ov.z = fmaf(gam, a[2], xv.z);
                ov.w = fmaf(gam, a[3], xv.w);
                *(float4*)(out + off) = ov;
            }
            {   // jf = 1 (wave1 slot 1, base 1024)
                f32x4 o = Rb[1024 + ((1*8 + cf) << 6) + l];
                f32x4 a = acc[1][cf];
                a[0]+=o[0]; a[1]+=o[1]; a[2]+=o[2]; a[3]+=o[3];
                const int c = cbase + cf*16 + lr;
                const int j = jbase + 1*16 + lg*4;
                size_t off = ((size_t)(b*CCH + c))*NN + j;
                float4 xv = *(const float4*)(x + off);
                float4 ov;
                ov.x = fmaf(gam, a[0], xv.x);
                ov.y = fmaf(gam, a[1], xv.y);
                ov.z = fmaf(gam, a[2], xv.z);
                ov.w = fmaf(gam, a[3], xv.w);
                *(float4*)(out + off) = ov;
            }
        }
    } else if (wv == 1) {
        #pragma unroll
        for (int cf = 0; cf < 8; cf++) {
            {   // jf = 2 (wave0 slot 0, base 0)
                f32x4 o = Rb[((0*8 + cf) << 6) + l];
                f32x4 a = acc[2][cf];
                a[0]+=o[0]; a[1]+=o[1]; a[2]+=o[2]; a[3]+=o[3];
                const int c = cbase + cf*16 + lr;
                const int j = jbase + 2*16 + lg*4;
                size_t off = ((size_t)(b*CCH + c))*NN + j;
                float4 xv = *(const float4*)(x + off);
                float4 ov;
                ov.x = fmaf(gam, a[0], xv.x);
                ov.y = fmaf(gam, a[1], xv.y);
                ov.z = fmaf(gam, a[2], xv.z);
                ov.w = fmaf(gam, a[3], xv.w);
                *(float4*)(out + off) = ov;
            }
            {   // jf = 3 (wave0 slot 1, base 0)
                f32x4 o = Rb[((1*8 + cf) << 6) + l];
                f32x4 a = acc[3][cf];
                a[0]+=o[0]; a[1]+=o[1]; a[2]+=o[2]; a[3]+=o[3];
                const int c = cbase + cf*16 + lr;
                const int j = jbase + 3*16 + lg*4;
                size_t off = ((size_t)(b*CCH + c))*NN + j;
                float4 xv = *(const float4*)(x + off);
                float4 ov;
                ov.x = fmaf(gam, a[0], xv.x);
                ov.y = fmaf(gam, a[1], xv.y);
                ov.z = fmaf(gam, a[2], xv.z);
                ov.w = fmaf(gam, a[3], xv.w);
                *(float4*)(out + off) = ov;
            }
        }
    }
}

// ---------------------------------------------------------------- launch
extern "C" void kernel_launch(void* const* d_in, const int* in_sizes, int n_in,
                              void* d_out, int out_size, void* d_ws, size_t ws_size,
                              hipStream_t stream)
{
    (void)in_sizes; (void)n_in; (void)out_size; (void)ws_size;
    const float* x     = (const float*)d_in[0];
    const float* wq    = (const float*)d_in[1];
    const float* bq    = (const float*)d_in[2];
    const float* wk    = (const float*)d_in[3];
    const float* bk    = (const float*)d_in[4];
    const float* wv    = (const float*)d_in[5];
    const float* bv    = (const float*)d_in[6];
    const float* gamma = (const float*)d_in[7];
    float* out = (float*)d_out;

    char* ws = (char*)d_ws;
    _Float16* q16  = (_Float16*)(ws + 0x000000);  // 1MB (f16 single)
    _Float16* k_hi = (_Float16*)(ws + 0x100000);  // 1MB (f16 hi)
    _Float16* k_lo = (_Float16*)(ws + 0x200000);  // 1MB (f16 lo)
    _Float16* v16  = (_Float16*)(ws + 0x400000);  // 8MB blocked
    float*    Sx   = (float*)   (ws + 0xC00000);  // 64KB (SL = log2 Z)
    unsigned short* wqh = (unsigned short*)(ws + 0xC10000);  // 16KB blocked
    unsigned short* wql = (unsigned short*)(ws + 0xC14000);  // 16KB
    unsigned short* wkh = (unsigned short*)(ws + 0xC18000);  // 16KB
    unsigned short* wkl = (unsigned short*)(ws + 0xC1C000);  // 16KB
    unsigned short* wvh = (unsigned short*)(ws + 0xC20000);  // 128KB
    unsigned short* wvl = (unsigned short*)(ws + 0xC40000);  // 128KB

    prep_w_blk  <<<dim3(320),      256, 0, stream>>>(
        wq, wk, wv, wqh, wql, wkh, wkl, wvh, wvl);
    proj_qk     <<<dim3(64, 4),    256, 0, stream>>>(
        x, wqh, wql, bq, wkh, wkl, bk, q16, k_hi, k_lo);
    proj_v      <<<dim3(2, 64, 4), 512, 0, stream>>>(x, wvh, wvl, bv, v16);
    stats_kernel<<<dim3(128, 4),   512, 0, stream>>>(q16, k_hi, k_lo, Sx);
    attn_kernel <<<dim3(512),      256, 0, stream>>>(
        q16, k_hi, k_lo, v16, Sx, x, gamma, out);
}

// Round 18
// 96.872 us; speedup vs baseline: 1.3673x; 1.0454x over previous
//
#include <hip/hip_runtime.h>

#define NB 4
#define CCH 256
#define NN 4096
#define DD 32

typedef __attribute__((ext_vector_type(8))) short bf16x8;
typedef __attribute__((ext_vector_type(8))) _Float16 f16x8;
typedef __attribute__((ext_vector_type(4))) _Float16 f16x4;
typedef __attribute__((ext_vector_type(2))) __fp16 fp16x2;
typedef __attribute__((ext_vector_type(4))) float f32x4;

#define MFB(a,b,c) __builtin_amdgcn_mfma_f32_16x16x32_bf16(a,b,c,0,0,0)
#define MFH(a,b,c) __builtin_amdgcn_mfma_f32_16x16x32_f16(a,b,c,0,0,0)
#define L2E 1.44269504f

__device__ inline unsigned short f2bf(float f){
    union { float f; unsigned u; } v; v.f = f;
    unsigned r = v.u + 0x7fffu + ((v.u >> 16) & 1u);
    return (unsigned short)(r >> 16);
}
__device__ inline float bfval(unsigned short h){
    union { unsigned u; float f; } v; v.u = ((unsigned)h) << 16; return v.f;
}
// native transcendental: D = 2^S0 (exactly what SL-folded softmax needs)
__device__ inline float vexp2(float x){
    float r; asm("v_exp_f32 %0, %1" : "=v"(r) : "v"(x)); return r;
}
__device__ inline f16x4 pk4(float p0, float p1, float p2, float p3){
    union { fp16x2 h2[2]; f16x4 v; } u;
    u.h2[0] = __builtin_amdgcn_cvt_pkrtz(p0, p1);
    u.h2[1] = __builtin_amdgcn_cvt_pkrtz(p2, p3);
    return u.v;
}

// ---------------------------------------------------------------- prep_w_blk
// Convert w ONCE into MFMA-fragment-BLOCKED layout [tile][kc][lg][lr][8]
// so a wave's fragment load is 1KB CONTIGUOUS (R29 fix; R28 evidence was
// proj MfmaUtil 4.4% from 1KB-stride 16B loads re-issued by 256 blocks).
__global__ __launch_bounds__(256) void prep_w_blk(
    const float* __restrict__ wq, const float* __restrict__ wk,
    const float* __restrict__ wv,
    unsigned short* __restrict__ wqh, unsigned short* __restrict__ wql,
    unsigned short* __restrict__ wkh, unsigned short* __restrict__ wkl,
    unsigned short* __restrict__ wvh, unsigned short* __restrict__ wvl)
{
    const int idx = blockIdx.x*256 + threadIdx.x;   // 0..81919 (grid 320)
    const float* src; unsigned short *dh, *dl; int d, c;
    if (idx < 8192)       { src = wq; dh = wqh; dl = wql; d = idx >> 8;           c = idx & 255; }
    else if (idx < 16384) { src = wk; dh = wkh; dl = wkl; d = (idx-8192) >> 8;    c = idx & 255; }
    else                  { src = wv; dh = wvh; dl = wvl; d = (idx-16384) >> 8;   c = idx & 255; }
    float v = src[d*CCH + c];
    const int tile = d >> 4, lr = d & 15;
    const int kc = c >> 5, lg = (c >> 3) & 3, e = c & 7;
    const int off = ((((tile*8 + kc)*4 + lg)*16) + lr)*8 + e;
    unsigned short h = f2bf(v);
    dh[off] = h;
    dl[off] = f2bf(v - bfval(h));
}

// ---------------------------------------------------------------- proj_fused
// R31: proj_qk + proj_v re-fused into ONE dispatch (R28's grid(3,nb,b)
// path-select was innocent -- its 65us was the uncoalesced w loads, now
// fixed by the blocked layout). Saves a launch gap; qk/V blocks co-schedule.
// ob<2: V path (output BLOCKED v16[b][ib=n/8][c][8]); ob==2: q/k path.
// q = single f16; k = f16 hi/lo pair.
__global__ __launch_bounds__(512) void proj_fused(
    const float* __restrict__ x,
    const unsigned short* __restrict__ wqh, const unsigned short* __restrict__ wql,
    const float* __restrict__ bq,
    const unsigned short* __restrict__ wkh, const unsigned short* __restrict__ wkl,
    const float* __restrict__ bk,
    const unsigned short* __restrict__ wvh, const unsigned short* __restrict__ wvl,
    const float* __restrict__ bv,
    _Float16* __restrict__ q16,
    _Float16* __restrict__ k_hi, _Float16* __restrict__ k_lo,
    _Float16* __restrict__ v16)
{
    const int ob = blockIdx.x;   // 0,1: V c-halves; 2: q/k
    const int nb = blockIdx.y;
    const int b  = blockIdx.z;
    const int t = threadIdx.x;
    const int l = t & 63;
    const int lr = l & 15, lg = l >> 4;
    const float* xb = x + (size_t)b*CCH*NN;

    if (ob < 2) {
        // ---------------- V path ----------------
        const int w = t >> 6;
        const int cg = w >> 2;
        const int ng = w & 3;
        const int n0 = nb*64 + ng*16;
        const int n  = n0 + lr;
        const int cbase0 = ob*128 + cg*64;
        const int ctile0 = ob*8 + cg*4;

        f32x4 acc[4] = {};

        for (int kc = 0; kc < 8; kc++) {
            const int kbase = kc*32 + lg*8;
            float xv[8];
            #pragma unroll
            for (int e = 0; e < 8; e++)
                xv[e] = xb[(size_t)(kbase + e)*NN + n];
            bf16x8 xh, xl;
            #pragma unroll
            for (int e = 0; e < 8; e++) {
                unsigned short h = f2bf(xv[e]);
                xh[e] = (short)h;
                xl[e] = (short)f2bf(xv[e] - bfval(h));
            }
            #pragma unroll
            for (int f = 0; f < 4; f++) {
                const int off = ((((ctile0 + f)*8 + kc)*4 + lg)*16 + lr)*8;
                bf16x8 wh = *(const bf16x8*)(wvh + off);
                bf16x8 wl = *(const bf16x8*)(wvl + off);
                acc[f] = MFB(wl, xh, acc[f]);
                acc[f] = MFB(wh, xl, acc[f]);
                acc[f] = MFB(wh, xh, acc[f]);
            }
        }

        const size_t bslice = (size_t)b*(NN/8);
        #pragma unroll
        for (int f = 0; f < 4; f++) {
            #pragma unroll
            for (int r = 0; r < 4; r++) {
                int c = cbase0 + f*16 + lg*4 + r;
                float val = acc[f][r] + bv[c];
                v16[(((bslice + (n >> 3))*CCH + c) << 3) + (n & 7)] =
                    (_Float16)val;
            }
        }
    } else {
        // ------------- q/k path (8 waves: fp = w>>2, ng = w&3) -------------
        const int w = t >> 6;
        const int fp = w >> 2;       // 0: q, 1: k
        const int ng = w & 3;
        const int n0 = nb*64 + ng*16;
        const int n  = n0 + lr;

        f32x4 acc[2] = {};

        for (int kc = 0; kc < 8; kc++) {
            const int cbase = kc*32 + lg*8;
            float xv[8];
            #pragma unroll
            for (int e = 0; e < 8; e++)
                xv[e] = xb[(size_t)(cbase + e)*NN + n];
            bf16x8 xh, xl;
            #pragma unroll
            for (int e = 0; e < 8; e++) {
                unsigned short h = f2bf(xv[e]);
                xh[e] = (short)h;
                xl[e] = (short)f2bf(xv[e] - bfval(h));
            }
            #pragma unroll
            for (int fl = 0; fl < 2; fl++) {
                const int off = (((fl*8 + kc)*4 + lg)*16 + lr)*8;
                const unsigned short* ph = (fp == 0) ? wqh : wkh;
                const unsigned short* pl = (fp == 0) ? wql : wkl;
                bf16x8 wh = *(const bf16x8*)(ph + off);
                bf16x8 wl = *(const bf16x8*)(pl + off);
                acc[fl] = MFB(xh, wl, acc[fl]);
                acc[fl] = MFB(xl, wh, acc[fl]);
                acc[fl] = MFB(xh, wh, acc[fl]);
            }
        }

        #pragma unroll
        for (int fl = 0; fl < 2; fl++) {
            const int d = fl*16 + lr;
            float bias = fp ? bk[d] : bq[d];
            #pragma unroll
            for (int r = 0; r < 4; r++) {
                int nn = n0 + lg*4 + r;
                float val = acc[fl][r] + bias;
                size_t a = ((size_t)(b*NN + nn))*DD + d;
                if (fp == 0) {
                    q16[a] = (_Float16)val;
                } else {
                    _Float16 h = (_Float16)val;
                    k_hi[a] = h;
                    k_lo[a] = (_Float16)(val - (float)h);
                }
            }
        }
    }
}

// ---------------------------------------------------------------- stats
// R31: i-tile 32 -> 64 (grid (64,4)): halves the k re-read L2 traffic
// (512 blocks x 1MB = 512MB -> 256MB). combine stays fused (Sx = log2 Z).
__global__ __launch_bounds__(512) void stats_kernel(
    const _Float16* __restrict__ q16,
    const _Float16* __restrict__ kh, const _Float16* __restrict__ kl,
    float* __restrict__ Sx)
{
    __shared__ float zW[8][64];
    const int t = threadIdx.x;
    const int w = t >> 6;
    const int l = t & 63;
    const int lr = l & 15, lg = l >> 4;
    const int it = blockIdx.x;   // 0..63 : i-tile (64 rows each)
    const int b  = blockIdx.y;
    const int ibase = it*64;
    const f32x4 zero = {0.f,0.f,0.f,0.f};

    f16x8 qf[4];
    #pragma unroll
    for (int f = 0; f < 4; f++) {
        size_t a = ((size_t)(b*NN + ibase + f*16 + lr))*DD + lg*8;
        qf[f] = *(const f16x8*)(q16 + a);
    }
    float Z[4] = {0.f, 0.f, 0.f, 0.f};

    const size_t k0 = ((size_t)(b*NN + w*16 + lr))*DD + lg*8;
    const _Float16* kp  = kh + k0;
    const _Float16* klp = kl + k0;

    for (int jt = 0; jt < 32; ++jt) {
        f16x8 kh2 = *(const f16x8*)kp;
        f16x8 kl2 = *(const f16x8*)klp;
        #pragma unroll
        for (int f = 0; f < 4; f++) {
            f32x4 e = MFH(kl2, qf[f], zero);
            e = MFH(kh2, qf[f], e);
            Z[f] += vexp2(e[0]*L2E) + vexp2(e[1]*L2E)
                  + vexp2(e[2]*L2E) + vexp2(e[3]*L2E);
        }
        kp  += 128*DD;
        klp += 128*DD;
    }
    #pragma unroll
    for (int f = 0; f < 4; f++) {
        Z[f] += __shfl_xor(Z[f], 16, 64);
        Z[f] += __shfl_xor(Z[f], 32, 64);
        if (lg == 0) zW[w][f*16 + lr] = Z[f];
    }
    __syncthreads();
    if (t < 64) {
        float z = 0.f;
        #pragma unroll
        for (int w2 = 0; w2 < 8; ++w2) z += zW[w2][t];
        Sx[(size_t)b*NN + ibase + t] = log2f(z);
    }
}

// ---------------------------------------------------------------- attn
// R30 final form (practical plateau for this decomposition: MFMA busy
// 21.8us == full-rate floor; 252 total regs/wave pins 2 waves/SIMD --
// every 4-wave variant requires acc<=64 i.e. doubled traffic, measured
// net-negative in R24/R25). sigma-permuted q rows -> K=32 full-rate PV;
// phase-split step; 32KB sequential end-reduce.
__global__ __launch_bounds__(256, 2) void attn_kernel(
    const _Float16* __restrict__ q16,
    const _Float16* __restrict__ kh16, const _Float16* __restrict__ kl16,
    const _Float16* __restrict__ v16,
    const float* __restrict__ Sx,
    const float* __restrict__ x, const float* __restrict__ gamma,
    float* __restrict__ out)
{
    __shared__ __align__(16) f32x4 Rb[2048];   // 32KB end-reduce buffer

    const int t = threadIdx.x;
    const int wv = t >> 6;       // i-quarter 0..3
    const int l = t & 63;
    const int lr = l & 15, lg = l >> 4;

    // XCD slice: lin&7 = (b,ct) -> one slice per XCD (~1.8MB, L2-resident).
    const int lin = blockIdx.x;
    const int slice = lin & 7;
    const int b   = slice >> 1;
    const int ct  = slice & 1;
    const int jt  = lin >> 3;    // 0..63
    const int jbase = jt*64, cbase = ct*128;

    // K B-fragments: 4 j-frags, f16 hi/lo (persistent; 32 VGPR)
    f16x8 kfh[4], kfl[4];
    #pragma unroll
    for (int jf = 0; jf < 4; jf++) {
        size_t a = ((size_t)(b*NN + jbase + jf*16 + lr))*DD + lg*8;
        kfh[jf] = *(const f16x8*)(kh16 + a);
        kfl[jf] = *(const f16x8*)(kl16 + a);
    }

    const float* Sb = Sx + (size_t)b*NN;
    const _Float16* vb = v16 + (size_t)b*(NN/8)*CCH*8;

    const int i0 = wv*1024;     // this wave's i-quarter; 32 steps of 32

    // sigma-permuted q pointers: step A rows 8(lr>>2)+(lr&3), step B +4
    const int sigma = 8*(lr >> 2) + (lr & 3);
    const _Float16* qpA = q16 + ((size_t)(b*NN + i0 + sigma))*DD + lg*8;
    const _Float16* qpB = qpA + 4*DD;
    // s pointers follow sigma: lane lg covers i = 8lg+r (A), 8lg+4+r (B)
    const float* spA = Sb + i0 + 8*lg;
    const float* spB = spA + 4;
    // V B-frag: lane (lr,lg) reads 16B block ib = i0/8 + lg, c = ..+lr
    const _Float16* vp = vb + (((size_t)(i0/8 + lg)*CCH + cbase + lr) << 3);

    f32x4 acc[4][8] = {};   // [jf][cf] -- ONLY static subscripts below!

    #pragma clang loop unroll(disable)
    for (int s = 0; s < 32; ++s) {
        // loads for THIS step (L2-resident; TLP hides the latency)
        f16x8 qA = *(const f16x8*)qpA;  qpA += 32*DD;
        f16x8 qB = *(const f16x8*)qpB;  qpB += 32*DD;
        float4 sA4 = *(const float4*)spA; spA += 32;
        float4 sB4 = *(const float4*)spB; spB += 32;
        f16x8 vv[8];
        #pragma unroll
        for (int cf = 0; cf < 8; cf++)
            vv[cf] = *(const f16x8*)(vp + cf*128);
        vp += 32*CCH;

        // ---- Phase 1: all 4 jf QK + exp + pack (independent chains) ----
        f16x8 pa[4];
        #pragma unroll
        for (int jf = 0; jf < 4; jf++) {
            f32x4 eA = {};
            eA = MFH(qA, kfl[jf], eA);
            eA = MFH(qA, kfh[jf], eA);
            f32x4 eB = {};
            eB = MFH(qB, kfl[jf], eB);
            eB = MFH(qB, kfh[jf], eB);
            union { f16x4 h4[2]; f16x8 h8; } pu;
            pu.h4[0] = pk4(vexp2(fmaf(eA[0], L2E, -sA4.x)),
                           vexp2(fmaf(eA[1], L2E, -sA4.y)),
                           vexp2(fmaf(eA[2], L2E, -sA4.z)),
                           vexp2(fmaf(eA[3], L2E, -sA4.w)));
            pu.h4[1] = pk4(vexp2(fmaf(eB[0], L2E, -sB4.x)),
                           vexp2(fmaf(eB[1], L2E, -sB4.y)),
                           vexp2(fmaf(eB[2], L2E, -sB4.z)),
                           vexp2(fmaf(eB[3], L2E, -sB4.w)));
            pa[jf] = pu.h8;
        }

        // ---- Phase 2: ONE un-fenced PV cluster (32 full-rate MFH) ----
        __builtin_amdgcn_s_setprio(1);
        #pragma unroll
        for (int jf = 0; jf < 4; jf++)
            #pragma unroll
            for (int cf = 0; cf < 8; cf++)
                acc[jf][cf] = MFH(pa[jf], vv[cf], acc[jf][cf]);
        __builtin_amdgcn_s_setprio(0);
    }

    // --------- 32KB sequential reduce over the 4 i-quarters ---------
    // slot(jf,cf) = (jf*8+cf)<<6 | lane.  All acc subscripts literal.
    // Phase A: wv2 dumps; wv0 accumulates.
    if (wv == 2) {
        #pragma unroll
        for (int jf = 0; jf < 4; jf++)
            #pragma unroll
            for (int cf = 0; cf < 8; cf++)
                Rb[((jf*8 + cf) << 6) + l] = acc[jf][cf];
    }
    __syncthreads();
    if (wv == 0) {
        #pragma unroll
        for (int jf = 0; jf < 4; jf++)
            #pragma unroll
            for (int cf = 0; cf < 8; cf++)
                acc[jf][cf] += Rb[((jf*8 + cf) << 6) + l];
    }
    __syncthreads();
    // Phase B: wv3 dumps; wv1 accumulates.
    if (wv == 3) {
        #pragma unroll
        for (int jf = 0; jf < 4; jf++)
            #pragma unroll
            for (int cf = 0; cf < 8; cf++)
                Rb[((jf*8 + cf) << 6) + l] = acc[jf][cf];
    }
    __syncthreads();
    if (wv == 1) {
        #pragma unroll
        for (int jf = 0; jf < 4; jf++)
            #pragma unroll
            for (int cf = 0; cf < 8; cf++)
                acc[jf][cf] += Rb[((jf*8 + cf) << 6) + l];
    }
    __syncthreads();
    // Phase C: jf-half exchange. wv0 gives jf{2,3} at base 0 (slots 0,1);
    //          wv1 gives jf{0,1} at base 1024 (slots 0,1).
    if (wv == 0) {
        #pragma unroll
        for (int cf = 0; cf < 8; cf++) {
            Rb[((0*8 + cf) << 6) + l] = acc[2][cf];
            Rb[((1*8 + cf) << 6) + l] = acc[3][cf];
        }
    } else if (wv == 1) {
        #pragma unroll
        for (int cf = 0; cf < 8; cf++) {
            Rb[1024 + ((0*8 + cf) << 6) + l] = acc[0][cf];
            Rb[1024 + ((1*8 + cf) << 6) + l] = acc[1][cf];
        }
    }
    __syncthreads();

    const float gam = gamma[0];
    // Phase D: wv0 outputs jf {0,1} (+ wave1's at base 1024);
    //          wv1 outputs jf {2,3} (+ wave0's at base 0).
    if (wv == 0) {
        #pragma unroll
        for (int cf = 0; cf < 8; cf++) {
            {   // jf = 0 (wave1 slot 0, base 1024)
                f32x4 o = Rb[1024 + ((0*8 + cf) << 6) + l];
                f32x4 a = acc[0][cf];
                a[0]+=o[0]; a[1]+=o[1]; a[2]+=o[2]; a[3]+=o[3];
                const int c = cbase + cf*16 + lr;
                const int j = jbase + 0*16 + lg*4;
                size_t off = ((size_t)(b*CCH + c))*NN + j;
                float4 xv = *(const float4*)(x + off);
                float4 ov;
                ov.x = fmaf(gam, a[0], xv.x);
                ov.y = fmaf(gam, a[1], xv.y);
                ov.z = fmaf(gam, a[2], xv.z);
                ov.w = fmaf(gam, a[3], xv.w);
                *(float4*)(out + off) = ov;
            }
            {   // jf = 1 (wave1 slot 1, base 1024)
                f32x4 o = Rb[1024 + ((1*8 + cf) << 6) + l];
                f32x4 a = acc[1][cf];
                a[0]+=o[0]; a[1]+=o[1]; a[2]+=o[2]; a[3]+=o[3];
                const int c = cbase + cf*16 + lr;
                const int j = jbase + 1*16 + lg*4;
                size_t off = ((size_t)(b*CCH + c))*NN + j;
                float4 xv = *(const float4*)(x + off);
                float4 ov;
                ov.x = fmaf(gam, a[0], xv.x);
                ov.y = fmaf(gam, a[1], xv.y);
                ov.z = fmaf(gam, a[2], xv.z);
                ov.w = fmaf(gam, a[3], xv.w);
                *(float4*)(out + off) = ov;
            }
        }
    } else if (wv == 1) {
        #pragma unroll
        for (int cf = 0; cf < 8; cf++) {
            {   // jf = 2 (wave0 slot 0, base 0)
                f32x4 o = Rb[((0*8 + cf) << 6) + l];
                f32x4 a = acc[2][cf];
                a[0]+=o[0]; a[1]+=o[1]; a[2]+=o[2]; a[3]+=o[3];
                const int c = cbase + cf*16 + lr;
                const int j = jbase + 2*16 + lg*4;
                size_t off = ((size_t)(b*CCH + c))*NN + j;
                float4 xv = *(const float4*)(x + off);
                float4 ov;
                ov.x = fmaf(gam, a[0], xv.x);
                ov.y = fmaf(gam, a[1], xv.y);
                ov.z = fmaf(gam, a[2], xv.z);
                ov.w = fmaf(gam, a[3], xv.w);
                *(float4*)(out + off) = ov;
            }
            {   // jf = 3 (wave0 slot 1, base 0)
                f32x4 o = Rb[((1*8 + cf) << 6) + l];
                f32x4 a = acc[3][cf];
                a[0]+=o[0]; a[1]+=o[1]; a[2]+=o[2]; a[3]+=o[3];
                const int c = cbase + cf*16 + lr;
                const int j = jbase + 3*16 + lg*4;
                size_t off = ((size_t)(b*CCH + c))*NN + j;
                float4 xv = *(const float4*)(x + off);
                float4 ov;
                ov.x = fmaf(gam, a[0], xv.x);
                ov.y = fmaf(gam, a[1], xv.y);
                ov.z = fmaf(gam, a[2], xv.z);
                ov.w = fmaf(gam, a[3], xv.w);
                *(float4*)(out + off) = ov;
            }
        }
    }
}

// ---------------------------------------------------------------- launch
extern "C" void kernel_launch(void* const* d_in, const int* in_sizes, int n_in,
                              void* d_out, int out_size, void* d_ws, size_t ws_size,
                              hipStream_t stream)
{
    (void)in_sizes; (void)n_in; (void)out_size; (void)ws_size;
    const float* x     = (const float*)d_in[0];
    const float* wq    = (const float*)d_in[1];
    const float* bq    = (const float*)d_in[2];
    const float* wk    = (const float*)d_in[3];
    const float* bk    = (const float*)d_in[4];
    const float* wv    = (const float*)d_in[5];
    const float* bv    = (const float*)d_in[6];
    const float* gamma = (const float*)d_in[7];
    float* out = (float*)d_out;

    char* ws = (char*)d_ws;
    _Float16* q16  = (_Float16*)(ws + 0x000000);  // 1MB (f16 single)
    _Float16* k_hi = (_Float16*)(ws + 0x100000);  // 1MB (f16 hi)
    _Float16* k_lo = (_Float16*)(ws + 0x200000);  // 1MB (f16 lo)
    _Float16* v16  = (_Float16*)(ws + 0x400000);  // 8MB blocked
    float*    Sx   = (float*)   (ws + 0xC00000);  // 64KB (SL = log2 Z)
    unsigned short* wqh = (unsigned short*)(ws + 0xC10000);  // 16KB blocked
    unsigned short* wql = (unsigned short*)(ws + 0xC14000);  // 16KB
    unsigned short* wkh = (unsigned short*)(ws + 0xC18000);  // 16KB
    unsigned short* wkl = (unsigned short*)(ws + 0xC1C000);  // 16KB
    unsigned short* wvh = (unsigned short*)(ws + 0xC20000);  // 128KB
    unsigned short* wvl = (unsigned short*)(ws + 0xC40000);  // 128KB

    prep_w_blk  <<<dim3(320),      256, 0, stream>>>(
        wq, wk, wv, wqh, wql, wkh, wkl, wvh, wvl);
    proj_fused  <<<dim3(3, 64, 4), 512, 0, stream>>>(
        x, wqh, wql, bq, wkh, wkl, bk, wvh, wvl, bv,
        q16, k_hi, k_lo, v16);
    stats_kernel<<<dim3(64, 4),    512, 0, stream>>>(q16, k_hi, k_lo, Sx);
    attn_kernel <<<dim3(512),      256, 0, stream>>>(
        q16, k_hi, k_lo, v16, Sx, x, gamma, out);
}

// Round 20
// 96.452 us; speedup vs baseline: 1.3732x; 1.0044x over previous
//
#include <hip/hip_runtime.h>

#define NB 4
#define CCH 256
#define NN 4096
#define DD 32

typedef __attribute__((ext_vector_type(8))) short bf16x8;
typedef __attribute__((ext_vector_type(8))) _Float16 f16x8;
typedef __attribute__((ext_vector_type(4))) _Float16 f16x4;
typedef __attribute__((ext_vector_type(2))) __fp16 fp16x2;
typedef __attribute__((ext_vector_type(4))) float f32x4;

#define MFB(a,b,c) __builtin_amdgcn_mfma_f32_16x16x32_bf16(a,b,c,0,0,0)
#define MFH(a,b,c) __builtin_amdgcn_mfma_f32_16x16x32_f16(a,b,c,0,0,0)
#define L2E 1.44269504f

__device__ inline unsigned short f2bf(float f){
    union { float f; unsigned u; } v; v.f = f;
    unsigned r = v.u + 0x7fffu + ((v.u >> 16) & 1u);
    return (unsigned short)(r >> 16);
}
__device__ inline float bfval(unsigned short h){
    union { unsigned u; float f; } v; v.u = ((unsigned)h) << 16; return v.f;
}
// native transcendental: D = 2^S0 (exactly what SL-folded softmax needs)
__device__ inline float vexp2(float x){
    float r; asm("v_exp_f32 %0, %1" : "=v"(r) : "v"(x)); return r;
}
__device__ inline f16x4 pk4(float p0, float p1, float p2, float p3){
    union { fp16x2 h2[2]; f16x4 v; } u;
    u.h2[0] = __builtin_amdgcn_cvt_pkrtz(p0, p1);
    u.h2[1] = __builtin_amdgcn_cvt_pkrtz(p2, p3);
    return u.v;
}

// ---------------------------------------------------------------- prep_w_blk
// Convert w ONCE into MFMA-fragment-BLOCKED layout [tile][kc][lg][lr][8]
// so a wave's fragment load is 1KB CONTIGUOUS (R29 fix; R28 evidence was
// proj MfmaUtil 4.4% from 1KB-stride 16B loads re-issued by 256 blocks).
__global__ __launch_bounds__(256) void prep_w_blk(
    const float* __restrict__ wq, const float* __restrict__ wk,
    const float* __restrict__ wv,
    unsigned short* __restrict__ wqh, unsigned short* __restrict__ wql,
    unsigned short* __restrict__ wkh, unsigned short* __restrict__ wkl,
    unsigned short* __restrict__ wvh, unsigned short* __restrict__ wvl)
{
    const int idx = blockIdx.x*256 + threadIdx.x;   // 0..81919 (grid 320)
    const float* src; unsigned short *dh, *dl; int d, c;
    if (idx < 8192)       { src = wq; dh = wqh; dl = wql; d = idx >> 8;           c = idx & 255; }
    else if (idx < 16384) { src = wk; dh = wkh; dl = wkl; d = (idx-8192) >> 8;    c = idx & 255; }
    else                  { src = wv; dh = wvh; dl = wvl; d = (idx-16384) >> 8;   c = idx & 255; }
    float v = src[d*CCH + c];
    const int tile = d >> 4, lr = d & 15;
    const int kc = c >> 5, lg = (c >> 3) & 3, e = c & 7;
    const int off = ((((tile*8 + kc)*4 + lg)*16) + lr)*8 + e;
    unsigned short h = f2bf(v);
    dh[off] = h;
    dl[off] = f2bf(v - bfval(h));
}

// ---------------------------------------------------------------- proj_fused
// proj_qk + proj_v fused into ONE dispatch (R31; the R28 65us failure was
// the uncoalesced w loads, fixed by the blocked layout).
// ob<2: V path (output BLOCKED v16[b][ib=n/8][c][8]); ob==2: q/k path.
// q = single f16; k = f16 hi/lo pair.
__global__ __launch_bounds__(512) void proj_fused(
    const float* __restrict__ x,
    const unsigned short* __restrict__ wqh, const unsigned short* __restrict__ wql,
    const float* __restrict__ bq,
    const unsigned short* __restrict__ wkh, const unsigned short* __restrict__ wkl,
    const float* __restrict__ bk,
    const unsigned short* __restrict__ wvh, const unsigned short* __restrict__ wvl,
    const float* __restrict__ bv,
    _Float16* __restrict__ q16,
    _Float16* __restrict__ k_hi, _Float16* __restrict__ k_lo,
    _Float16* __restrict__ v16)
{
    const int ob = blockIdx.x;   // 0,1: V c-halves; 2: q/k
    const int nb = blockIdx.y;
    const int b  = blockIdx.z;
    const int t = threadIdx.x;
    const int l = t & 63;
    const int lr = l & 15, lg = l >> 4;
    const float* xb = x + (size_t)b*CCH*NN;

    if (ob < 2) {
        // ---------------- V path ----------------
        const int w = t >> 6;
        const int cg = w >> 2;
        const int ng = w & 3;
        const int n0 = nb*64 + ng*16;
        const int n  = n0 + lr;
        const int cbase0 = ob*128 + cg*64;
        const int ctile0 = ob*8 + cg*4;

        f32x4 acc[4] = {};

        for (int kc = 0; kc < 8; kc++) {
            const int kbase = kc*32 + lg*8;
            float xv[8];
            #pragma unroll
            for (int e = 0; e < 8; e++)
                xv[e] = xb[(size_t)(kbase + e)*NN + n];
            bf16x8 xh, xl;
            #pragma unroll
            for (int e = 0; e < 8; e++) {
                unsigned short h = f2bf(xv[e]);
                xh[e] = (short)h;
                xl[e] = (short)f2bf(xv[e] - bfval(h));
            }
            #pragma unroll
            for (int f = 0; f < 4; f++) {
                const int off = ((((ctile0 + f)*8 + kc)*4 + lg)*16 + lr)*8;
                bf16x8 wh = *(const bf16x8*)(wvh + off);
                bf16x8 wl = *(const bf16x8*)(wvl + off);
                acc[f] = MFB(wl, xh, acc[f]);
                acc[f] = MFB(wh, xl, acc[f]);
                acc[f] = MFB(wh, xh, acc[f]);
            }
        }

        const size_t bslice = (size_t)b*(NN/8);
        #pragma unroll
        for (int f = 0; f < 4; f++) {
            #pragma unroll
            for (int r = 0; r < 4; r++) {
                int c = cbase0 + f*16 + lg*4 + r;
                float val = acc[f][r] + bv[c];
                v16[(((bslice + (n >> 3))*CCH + c) << 3) + (n & 7)] =
                    (_Float16)val;
            }
        }
    } else {
        // ------------- q/k path (8 waves: fp = w>>2, ng = w&3) -------------
        const int w = t >> 6;
        const int fp = w >> 2;       // 0: q, 1: k
        const int ng = w & 3;
        const int n0 = nb*64 + ng*16;
        const int n  = n0 + lr;

        f32x4 acc[2] = {};

        for (int kc = 0; kc < 8; kc++) {
            const int cbase = kc*32 + lg*8;
            float xv[8];
            #pragma unroll
            for (int e = 0; e < 8; e++)
                xv[e] = xb[(size_t)(cbase + e)*NN + n];
            bf16x8 xh, xl;
            #pragma unroll
            for (int e = 0; e < 8; e++) {
                unsigned short h = f2bf(xv[e]);
                xh[e] = (short)h;
                xl[e] = (short)f2bf(xv[e] - bfval(h));
            }
            #pragma unroll
            for (int fl = 0; fl < 2; fl++) {
                const int off = (((fl*8 + kc)*4 + lg)*16 + lr)*8;
                const unsigned short* ph = (fp == 0) ? wqh : wkh;
                const unsigned short* pl = (fp == 0) ? wql : wkl;
                bf16x8 wh = *(const bf16x8*)(ph + off);
                bf16x8 wl = *(const bf16x8*)(pl + off);
                acc[fl] = MFB(xh, wl, acc[fl]);
                acc[fl] = MFB(xl, wh, acc[fl]);
                acc[fl] = MFB(xh, wh, acc[fl]);
            }
        }

        #pragma unroll
        for (int fl = 0; fl < 2; fl++) {
            const int d = fl*16 + lr;
            float bias = fp ? bk[d] : bq[d];
            #pragma unroll
            for (int r = 0; r < 4; r++) {
                int nn = n0 + lg*4 + r;
                float val = acc[fl][r] + bias;
                size_t a = ((size_t)(b*NN + nn))*DD + d;
                if (fp == 0) {
                    q16[a] = (_Float16)val;
                } else {
                    _Float16 h = (_Float16)val;
                    k_hi[a] = h;
                    k_lo[a] = (_Float16)(val - (float)h);
                }
            }
        }
    }
}

// ---------------------------------------------------------------- stats
// i-tile 64, grid (64,4); combine fused (Sx = log2 Z).
__global__ __launch_bounds__(512) void stats_kernel(
    const _Float16* __restrict__ q16,
    const _Float16* __restrict__ kh, const _Float16* __restrict__ kl,
    float* __restrict__ Sx)
{
    __shared__ float zW[8][64];
    const int t = threadIdx.x;
    const int w = t >> 6;
    const int l = t & 63;
    const int lr = l & 15, lg = l >> 4;
    const int it = blockIdx.x;   // 0..63 : i-tile (64 rows each)
    const int b  = blockIdx.y;
    const int ibase = it*64;
    const f32x4 zero = {0.f,0.f,0.f,0.f};

    f16x8 qf[4];
    #pragma unroll
    for (int f = 0; f < 4; f++) {
        size_t a = ((size_t)(b*NN + ibase + f*16 + lr))*DD + lg*8;
        qf[f] = *(const f16x8*)(q16 + a);
    }
    float Z[4] = {0.f, 0.f, 0.f, 0.f};

    const size_t k0 = ((size_t)(b*NN + w*16 + lr))*DD + lg*8;
    const _Float16* kp  = kh + k0;
    const _Float16* klp = kl + k0;

    for (int jt = 0; jt < 32; ++jt) {
        f16x8 kh2 = *(const f16x8*)kp;
        f16x8 kl2 = *(const f16x8*)klp;
        #pragma unroll
        for (int f = 0; f < 4; f++) {
            f32x4 e = MFH(kl2, qf[f], zero);
            e = MFH(kh2, qf[f], e);
            Z[f] += vexp2(e[0]*L2E) + vexp2(e[1]*L2E)
                  + vexp2(e[2]*L2E) + vexp2(e[3]*L2E);
        }
        kp  += 128*DD;
        klp += 128*DD;
    }
    #pragma unroll
    for (int f = 0; f < 4; f++) {
        Z[f] += __shfl_xor(Z[f], 16, 64);
        Z[f] += __shfl_xor(Z[f], 32, 64);
        if (lg == 0) zW[w][f*16 + lr] = Z[f];
    }
    __syncthreads();
    if (t < 64) {
        float z = 0.f;
        #pragma unroll
        for (int w2 = 0; w2 < 8; ++w2) z += zW[w2][t];
        Sx[(size_t)b*NN + ibase + t] = log2f(z);
    }
}

// ---------------------------------------------------------------- attn
// R31 final form (best passing config, attn ~56us; MFMA busy 21.8us ==
// full-rate floor; 252 total regs/wave pins 2 waves/SIMD). R32's k_lo
// drop + L2E fold REVERTED: it failed absmax 2863 (vs 0.18 threshold),
// a magnitude my precision model cannot explain (k_lo bound <=0.03 log2
// even at 2^65-tail pairs) -- unexplained interaction, so full revert
// per rigor discipline. sigma-permuted q rows -> K=32 full-rate PV with
// zero shuffles; phase-split step; 32KB sequential end-reduce.
__global__ __launch_bounds__(256, 2) void attn_kernel(
    const _Float16* __restrict__ q16,
    const _Float16* __restrict__ kh16, const _Float16* __restrict__ kl16,
    const _Float16* __restrict__ v16,
    const float* __restrict__ Sx,
    const float* __restrict__ x, const float* __restrict__ gamma,
    float* __restrict__ out)
{
    __shared__ __align__(16) f32x4 Rb[2048];   // 32KB end-reduce buffer

    const int t = threadIdx.x;
    const int wv = t >> 6;       // i-quarter 0..3
    const int l = t & 63;
    const int lr = l & 15, lg = l >> 4;

    // XCD slice: lin&7 = (b,ct) -> one slice per XCD (~1.8MB, L2-resident).
    const int lin = blockIdx.x;
    const int slice = lin & 7;
    const int b   = slice >> 1;
    const int ct  = slice & 1;
    const int jt  = lin >> 3;    // 0..63
    const int jbase = jt*64, cbase = ct*128;

    // K B-fragments: 4 j-frags, f16 hi/lo (persistent; 32 VGPR)
    f16x8 kfh[4], kfl[4];
    #pragma unroll
    for (int jf = 0; jf < 4; jf++) {
        size_t a = ((size_t)(b*NN + jbase + jf*16 + lr))*DD + lg*8;
        kfh[jf] = *(const f16x8*)(kh16 + a);
        kfl[jf] = *(const f16x8*)(kl16 + a);
    }

    const float* Sb = Sx + (size_t)b*NN;
    const _Float16* vb = v16 + (size_t)b*(NN/8)*CCH*8;

    const int i0 = wv*1024;     // this wave's i-quarter; 32 steps of 32

    // sigma-permuted q pointers: step A rows 8(lr>>2)+(lr&3), step B +4
    const int sigma = 8*(lr >> 2) + (lr & 3);
    const _Float16* qpA = q16 + ((size_t)(b*NN + i0 + sigma))*DD + lg*8;
    const _Float16* qpB = qpA + 4*DD;
    // s pointers follow sigma: lane lg covers i = 8lg+r (A), 8lg+4+r (B)
    const float* spA = Sb + i0 + 8*lg;
    const float* spB = spA + 4;
    // V B-frag: lane (lr,lg) reads 16B block ib = i0/8 + lg, c = ..+lr
    const _Float16* vp = vb + (((size_t)(i0/8 + lg)*CCH + cbase + lr) << 3);

    f32x4 acc[4][8] = {};   // [jf][cf] -- ONLY static subscripts below!

    #pragma clang loop unroll(disable)
    for (int s = 0; s < 32; ++s) {
        // loads for THIS step (L2-resident; TLP hides the latency)
        f16x8 qA = *(const f16x8*)qpA;  qpA += 32*DD;
        f16x8 qB = *(const f16x8*)qpB;  qpB += 32*DD;
        float4 sA4 = *(const float4*)spA; spA += 32;
        float4 sB4 = *(const float4*)spB; spB += 32;
        f16x8 vv[8];
        #pragma unroll
        for (int cf = 0; cf < 8; cf++)
            vv[cf] = *(const f16x8*)(vp + cf*128);
        vp += 32*CCH;

        // ---- Phase 1: all 4 jf QK + exp + pack (independent chains) ----
        f16x8 pa[4];
        #pragma unroll
        for (int jf = 0; jf < 4; jf++) {
            f32x4 eA = {};
            eA = MFH(qA, kfl[jf], eA);
            eA = MFH(qA, kfh[jf], eA);
            f32x4 eB = {};
            eB = MFH(qB, kfl[jf], eB);
            eB = MFH(qB, kfh[jf], eB);
            union { f16x4 h4[2]; f16x8 h8; } pu;
            pu.h4[0] = pk4(vexp2(fmaf(eA[0], L2E, -sA4.x)),
                           vexp2(fmaf(eA[1], L2E, -sA4.y)),
                           vexp2(fmaf(eA[2], L2E, -sA4.z)),
                           vexp2(fmaf(eA[3], L2E, -sA4.w)));
            pu.h4[1] = pk4(vexp2(fmaf(eB[0], L2E, -sB4.x)),
                           vexp2(fmaf(eB[1], L2E, -sB4.y)),
                           vexp2(fmaf(eB[2], L2E, -sB4.z)),
                           vexp2(fmaf(eB[3], L2E, -sB4.w)));
            pa[jf] = pu.h8;
        }

        // ---- Phase 2: ONE un-fenced PV cluster (32 full-rate MFH) ----
        __builtin_amdgcn_s_setprio(1);
        #pragma unroll
        for (int jf = 0; jf < 4; jf++)
            #pragma unroll
            for (int cf = 0; cf < 8; cf++)
                acc[jf][cf] = MFH(pa[jf], vv[cf], acc[jf][cf]);
        __builtin_amdgcn_s_setprio(0);
    }

    // --------- 32KB sequential reduce over the 4 i-quarters ---------
    // slot(jf,cf) = (jf*8+cf)<<6 | lane.  All acc subscripts literal.
    // Phase A: wv2 dumps; wv0 accumulates.
    if (wv == 2) {
        #pragma unroll
        for (int jf = 0; jf < 4; jf++)
            #pragma unroll
            for (int cf = 0; cf < 8; cf++)
                Rb[((jf*8 + cf) << 6) + l] = acc[jf][cf];
    }
    __syncthreads();
    if (wv == 0) {
        #pragma unroll
        for (int jf = 0; jf < 4; jf++)
            #pragma unroll
            for (int cf = 0; cf < 8; cf++)
                acc[jf][cf] += Rb[((jf*8 + cf) << 6) + l];
    }
    __syncthreads();
    // Phase B: wv3 dumps; wv1 accumulates.
    if (wv == 3) {
        #pragma unroll
        for (int jf = 0; jf < 4; jf++)
            #pragma unroll
            for (int cf = 0; cf < 8; cf++)
                Rb[((jf*8 + cf) << 6) + l] = acc[jf][cf];
    }
    __syncthreads();
    if (wv == 1) {
        #pragma unroll
        for (int jf = 0; jf < 4; jf++)
            #pragma unroll
            for (int cf = 0; cf < 8; cf++)
                acc[jf][cf] += Rb[((jf*8 + cf) << 6) + l];
    }
    __syncthreads();
    // Phase C: jf-half exchange. wv0 gives jf{2,3} at base 0 (slots 0,1);
    //          wv1 gives jf{0,1} at base 1024 (slots 0,1).
    if (wv == 0) {
        #pragma unroll
        for (int cf = 0; cf < 8; cf++) {
            Rb[((0*8 + cf) << 6) + l] = acc[2][cf];
            Rb[((1*8 + cf) << 6) + l] = acc[3][cf];
        }
    } else if (wv == 1) {
        #pragma unroll
        for (int cf = 0; cf < 8; cf++) {
            Rb[1024 + ((0*8 + cf) << 6) + l] = acc[0][cf];
            Rb[1024 + ((1*8 + cf) << 6) + l] = acc[1][cf];
        }
    }
    __syncthreads();

    const float gam = gamma[0];
    // Phase D: wv0 outputs jf {0,1} (+ wave1's at base 1024);
    //          wv1 outputs jf {2,3} (+ wave0's at base 0).
    if (wv == 0) {
        #pragma unroll
        for (int cf = 0; cf < 8; cf++) {
            {   // jf = 0 (wave1 slot 0, base 1024)
                f32x4 o = Rb[1024 + ((0*8 + cf) << 6) + l];
                f32x4 a = acc[0][cf];
                a[0]+=o[0]; a[1]+=o[1]; a[2]+=o[2]; a[3]+=o[3];
                const int c = cbase + cf*16 + lr;
                const int j = jbase + 0*16 + lg*4;
                size_t off = ((size_t)(b*CCH + c))*NN + j;
                float4 xv = *(const float4*)(x + off);
                float4 ov;
                ov.x = fmaf(gam, a[0], xv.x);
                ov.y = fmaf(gam, a[1], xv.y);
                ov.z = fmaf(gam, a[2], xv.z);
                ov.w = fmaf(gam, a[3], xv.w);
                *(float4*)(out + off) = ov;
            }
            {   // jf = 1 (wave1 slot 1, base 1024)
                f32x4 o = Rb[1024 + ((1*8 + cf) << 6) + l];
                f32x4 a = acc[1][cf];
                a[0]+=o[0]; a[1]+=o[1]; a[2]+=o[2]; a[3]+=o[3];
                const int c = cbase + cf*16 + lr;
                const int j = jbase + 1*16 + lg*4;
                size_t off = ((size_t)(b*CCH + c))*NN + j;
                float4 xv = *(const float4*)(x + off);
                float4 ov;
                ov.x = fmaf(gam, a[0], xv.x);
                ov.y = fmaf(gam, a[1], xv.y);
                ov.z = fmaf(gam, a[2], xv.z);
                ov.w = fmaf(gam, a[3], xv.w);
                *(float4*)(out + off) = ov;
            }
        }
    } else if (wv == 1) {
        #pragma unroll
        for (int cf = 0; cf < 8; cf++) {
            {   // jf = 2 (wave0 slot 0, base 0)
                f32x4 o = Rb[((0*8 + cf) << 6) + l];
                f32x4 a = acc[2][cf];
                a[0]+=o[0]; a[1]+=o[1]; a[2]+=o[2]; a[3]+=o[3];
                const int c = cbase + cf*16 + lr;
                const int j = jbase + 2*16 + lg*4;
                size_t off = ((size_t)(b*CCH + c))*NN + j;
                float4 xv = *(const float4*)(x + off);
                float4 ov;
                ov.x = fmaf(gam, a[0], xv.x);
                ov.y = fmaf(gam, a[1], xv.y);
                ov.z = fmaf(gam, a[2], xv.z);
                ov.w = fmaf(gam, a[3], xv.w);
                *(float4*)(out + off) = ov;
            }
            {   // jf = 3 (wave0 slot 1, base 0)
                f32x4 o = Rb[((1*8 + cf) << 6) + l];
                f32x4 a = acc[3][cf];
                a[0]+=o[0]; a[1]+=o[1]; a[2]+=o[2]; a[3]+=o[3];
                const int c = cbase + cf*16 + lr;
                const int j = jbase + 3*16 + lg*4;
                size_t off = ((size_t)(b*CCH + c))*NN + j;
                float4 xv = *(const float4*)(x + off);
                float4 ov;
                ov.x = fmaf(gam, a[0], xv.x);
                ov.y = fmaf(gam, a[1], xv.y);
                ov.z = fmaf(gam, a[2], xv.z);
                ov.w = fmaf(gam, a[3], xv.w);
                *(float4*)(out + off) = ov;
            }
        }
    }
}

// ---------------------------------------------------------------- launch
extern "C" void kernel_launch(void* const* d_in, const int* in_sizes, int n_in,
                              void* d_out, int out_size, void* d_ws, size_t ws_size,
                              hipStream_t stream)
{
    (void)in_sizes; (void)n_in; (void)out_size; (void)ws_size;
    const float* x     = (const float*)d_in[0];
    const float* wq    = (const float*)d_in[1];
    const float* bq    = (const float*)d_in[2];
    const float* wk    = (const float*)d_in[3];
    const float* bk    = (const float*)d_in[4];
    const float* wv    = (const float*)d_in[5];
    const float* bv    = (const float*)d_in[6];
    const float* gamma = (const float*)d_in[7];
    float* out = (float*)d_out;

    char* ws = (char*)d_ws;
    _Float16* q16  = (_Float16*)(ws + 0x000000);  // 1MB (f16 single)
    _Float16* k_hi = (_Float16*)(ws + 0x100000);  // 1MB (f16 hi)
    _Float16* k_lo = (_Float16*)(ws + 0x200000);  // 1MB (f16 lo)
    _Float16* v16  = (_Float16*)(ws + 0x400000);  // 8MB blocked
    float*    Sx   = (float*)   (ws + 0xC00000);  // 64KB (SL = log2 Z)
    unsigned short* wqh = (unsigned short*)(ws + 0xC10000);  // 16KB blocked
    unsigned short* wql = (unsigned short*)(ws + 0xC14000);  // 16KB
    unsigned short* wkh = (unsigned short*)(ws + 0xC18000);  // 16KB
    unsigned short* wkl = (unsigned short*)(ws + 0xC1C000);  // 16KB
    unsigned short* wvh = (unsigned short*)(ws + 0xC20000);  // 128KB
    unsigned short* wvl = (unsigned short*)(ws + 0xC40000);  // 128KB

    prep_w_blk  <<<dim3(320),      256, 0, stream>>>(
        wq, wk, wv, wqh, wql, wkh, wkl, wvh, wvl);
    proj_fused  <<<dim3(3, 64, 4), 512, 0, stream>>>(
        x, wqh, wql, bq, wkh, wkl, bk, wvh, wvl, bv,
        q16, k_hi, k_lo, v16);
    stats_kernel<<<dim3(64, 4),    512, 0, stream>>>(q16, k_hi, k_lo, Sx);
    attn_kernel <<<dim3(512),      256, 0, stream>>>(
        q16, k_hi, k_lo, v16, Sx, x, gamma, out);
}